// Round 1
// baseline (5454.287 us; speedup 1.0000x reference)
//
#include <hip/hip_runtime.h>

// GCN 2-layer forward on MI355X.
// Pipeline:
//   K1: deg[i] = 1 (self-loop)
//   K2: deg[dst[e]] += 1                     (int atomics, 16M edges)
//   K3: dinv = rsqrt(deg); h1s = (x@W1)*dinv; agg1 = h1s*dinv (self-loop term)
//   K4: agg1[dst] += h1s[src]*dinv[dst]      (fp32 hw atomics, 4 comps/edge)
//   K5: h2s = (relu(agg1+b1)@W2)*dinv; out = b2 + h2s*dinv (self-loop term)
//   K6: out[dst] += h2s[src]*dinv[dst]       (fp32 hw atomics, 2 comps/edge)
// Workspace: deg(4N) | dinv(4N) | h1s(16N, reused as h2s) | agg1(16N) = 40MB.

constexpr int BLK = 256;

__global__ __launch_bounds__(BLK) void k_init_deg(unsigned* __restrict__ deg, int n) {
    int i = blockIdx.x * BLK + threadIdx.x;
    if (i < n) deg[i] = 1u;
}

__global__ __launch_bounds__(BLK) void k_count_deg(const int* __restrict__ dst,
                                                   unsigned* __restrict__ deg, int E) {
    int e = blockIdx.x * BLK + threadIdx.x;
    if (e < E) atomicAdd(&deg[dst[e]], 1u);
}

__global__ __launch_bounds__(BLK) void k_node1(const float2* __restrict__ x,
                                               const float* __restrict__ W1,
                                               const unsigned* __restrict__ deg,
                                               float* __restrict__ dinv,
                                               float4* __restrict__ h1s,
                                               float4* __restrict__ agg1, int n) {
    int i = blockIdx.x * BLK + threadIdx.x;
    if (i >= n) return;
    float dv = rsqrtf((float)deg[i]);
    dinv[i] = dv;
    float2 xv = x[i];
    float4 h;
    h.x = fmaf(xv.y, W1[4], xv.x * W1[0]);
    h.y = fmaf(xv.y, W1[5], xv.x * W1[1]);
    h.z = fmaf(xv.y, W1[6], xv.x * W1[2]);
    h.w = fmaf(xv.y, W1[7], xv.x * W1[3]);
    float4 hs = make_float4(h.x * dv, h.y * dv, h.z * dv, h.w * dv);
    h1s[i] = hs;
    // self-loop contribution: h1[i] * dinv[i]^2 = hs * dinv[i]
    agg1[i] = make_float4(hs.x * dv, hs.y * dv, hs.z * dv, hs.w * dv);
}

__global__ __launch_bounds__(BLK) void k_edge1(const int* __restrict__ src,
                                               const int* __restrict__ dst,
                                               const float* __restrict__ dinv,
                                               const float4* __restrict__ h1s,
                                               float* __restrict__ agg1, int E) {
    int e = blockIdx.x * BLK + threadIdx.x;
    if (e >= E) return;
    int s = src[e], d = dst[e];
    float w = dinv[d];
    float4 m = h1s[s];
    float* p = agg1 + 4ll * d;
    unsafeAtomicAdd(p + 0, m.x * w);
    unsafeAtomicAdd(p + 1, m.y * w);
    unsafeAtomicAdd(p + 2, m.z * w);
    unsafeAtomicAdd(p + 3, m.w * w);
}

__global__ __launch_bounds__(BLK) void k_node2(const float4* __restrict__ agg1,
                                               const float* __restrict__ b1,
                                               const float* __restrict__ W2,
                                               const float* __restrict__ b2,
                                               const float* __restrict__ dinv,
                                               float2* __restrict__ h2s,
                                               float2* __restrict__ out, int n) {
    int i = blockIdx.x * BLK + threadIdx.x;
    if (i >= n) return;
    float4 a = agg1[i];
    a.x = fmaxf(a.x + b1[0], 0.0f);
    a.y = fmaxf(a.y + b1[1], 0.0f);
    a.z = fmaxf(a.z + b1[2], 0.0f);
    a.w = fmaxf(a.w + b1[3], 0.0f);
    float dv = dinv[i];
    float2 h;
    h.x = a.x * W2[0] + a.y * W2[2] + a.z * W2[4] + a.w * W2[6];
    h.y = a.x * W2[1] + a.y * W2[3] + a.z * W2[5] + a.w * W2[7];
    h.x *= dv;
    h.y *= dv;
    h2s[i] = h;
    // out init = b2 + self-loop contribution h2[i]*dinv^2 = b2 + h*dinv
    out[i] = make_float2(b2[0] + h.x * dv, b2[1] + h.y * dv);
}

__global__ __launch_bounds__(BLK) void k_edge2(const int* __restrict__ src,
                                               const int* __restrict__ dst,
                                               const float* __restrict__ dinv,
                                               const float2* __restrict__ h2s,
                                               float* __restrict__ out, int E) {
    int e = blockIdx.x * BLK + threadIdx.x;
    if (e >= E) return;
    int s = src[e], d = dst[e];
    float w = dinv[d];
    float2 m = h2s[s];
    float* p = out + 2ll * d;
    unsafeAtomicAdd(p + 0, m.x * w);
    unsafeAtomicAdd(p + 1, m.y * w);
}

extern "C" void kernel_launch(void* const* d_in, const int* in_sizes, int n_in,
                              void* d_out, int out_size, void* d_ws, size_t ws_size,
                              hipStream_t stream) {
    const float* x  = (const float*)d_in[0];
    const int* ei   = (const int*)d_in[1];   // [2, E] int32 per harness contract
    const float* W1 = (const float*)d_in[2];
    const float* b1 = (const float*)d_in[3];
    const float* W2 = (const float*)d_in[4];
    const float* b2 = (const float*)d_in[5];
    float* out = (float*)d_out;

    const int N = in_sizes[0] / 2;
    const int E = in_sizes[1] / 2;
    const int* src = ei;
    const int* dst = ei + E;

    char* ws = (char*)d_ws;
    unsigned* deg = (unsigned*)(ws);                       // 4N bytes
    float* dinv   = (float*)(ws + (size_t)4 * N);          // 4N bytes
    float* h1s    = (float*)(ws + (size_t)8 * N);          // 16N bytes (reused: h2s)
    float* agg1   = (float*)(ws + (size_t)24 * N);         // 16N bytes
    float* h2s    = h1s;                                   // h1s dead after k_edge1

    const int gN = (N + BLK - 1) / BLK;
    const int gE = (E + BLK - 1) / BLK;

    k_init_deg<<<gN, BLK, 0, stream>>>(deg, N);
    k_count_deg<<<gE, BLK, 0, stream>>>(dst, deg, E);
    k_node1<<<gN, BLK, 0, stream>>>((const float2*)x, W1, deg, dinv,
                                    (float4*)h1s, (float4*)agg1, N);
    k_edge1<<<gE, BLK, 0, stream>>>(src, dst, dinv, (const float4*)h1s, agg1, E);
    k_node2<<<gN, BLK, 0, stream>>>((const float4*)agg1, b1, W2, b2, dinv,
                                    (float2*)h2s, (float2*)out, N);
    k_edge2<<<gE, BLK, 0, stream>>>(src, dst, dinv, (const float2*)h2s, out, E);
}

// Round 2
// 938.043 us; speedup vs baseline: 5.8145x; 5.8145x over previous
//
#include <hip/hip_runtime.h>

// GCN 2-layer forward, MI355X. R2: counting-sort edges by dst-window once,
// then LDS-accumulated per-window aggregation (no global fp32 atomics).
//
// Fast path pipeline (window W=1024 nodes, NB=ceil(N/W)=977 buckets):
//   zero   : bucket_cnt = 0
//   hist   : bucket_cnt[dst>>10] += 1           (LDS-aggregated)
//   scan   : bucket_base = exclusive_scan(cnt); bucket_fill = base
//   reorder: perm[pos] = src | (dst&1023)<<20   (block-LDS binning)
//   dinv   : per-bucket LDS degree count -> dinv = rsqrt(deg+1)
//   node1  : h1s = (x@W1)*dinv
//   acc1   : per-bucket LDS accumulate h1s[src]; agg1[d]=dinv[d]*(sum+h1s[d])
//   node2  : h2s = (relu(agg1+b1)@W2)*dinv
//   acc2   : per-bucket LDS accumulate h2s[src]; out[d]=dinv[d]*(sum+h2s[d])+b2
// dinv[dst] is factored out of the edge sum (applied once at flush).
// Workspace: 32KB counters | dinv 4N | h1s 16N | agg1 16N | perm 4E  (~100MB).
// Falls back to the R1 global-atomic path if ws_size is too small.

constexpr int W_SHIFT = 10;
constexpr int W = 1024;            // nodes per bucket window
constexpr int MAXB = 1024;         // max buckets (LDS arrays sized to this)
constexpr int RB = 256;            // reorder block threads
constexpr int CHUNK = 4096;        // edges per reorder block
constexpr int AB = 512;            // accumulate block threads

// ---------------- fast path kernels ----------------

__global__ __launch_bounds__(256) void k_zero(unsigned* __restrict__ cnt, int nb) {
    int i = blockIdx.x * 256 + threadIdx.x;
    if (i < nb) cnt[i] = 0u;
}

__global__ __launch_bounds__(256) void k_hist(const int* __restrict__ dst,
                                              unsigned* __restrict__ cnt, int E, int nb) {
    __shared__ unsigned h[MAXB];
    for (int i = threadIdx.x; i < nb; i += 256) h[i] = 0u;
    __syncthreads();
    for (long e = blockIdx.x * 256l + threadIdx.x; e < E; e += (long)gridDim.x * 256)
        atomicAdd(&h[((unsigned)dst[e]) >> W_SHIFT], 1u);
    __syncthreads();
    for (int i = threadIdx.x; i < nb; i += 256) {
        unsigned v = h[i];
        if (v) atomicAdd(&cnt[i], v);
    }
}

__global__ __launch_bounds__(1024) void k_scan(const unsigned* __restrict__ cnt,
                                               unsigned* __restrict__ base,
                                               unsigned* __restrict__ fill, int nb) {
    __shared__ unsigned s[1024];
    int t = threadIdx.x;
    unsigned v = (t < nb) ? cnt[t] : 0u;
    s[t] = v;
    __syncthreads();
    for (int off = 1; off < 1024; off <<= 1) {
        unsigned u = (t >= off) ? s[t - off] : 0u;
        __syncthreads();
        s[t] += u;
        __syncthreads();
    }
    unsigned ex = s[t] - v;   // exclusive
    if (t < nb) { base[t] = ex; fill[t] = ex; }
    if (t == 1023) base[nb] = s[1023];
}

__global__ __launch_bounds__(RB) void k_reorder(const int* __restrict__ src,
                                                const int* __restrict__ dst,
                                                unsigned* __restrict__ fill,
                                                unsigned* __restrict__ perm,
                                                int E, int nb) {
    __shared__ unsigned hist[MAXB];
    __shared__ unsigned sval[CHUNK];
    __shared__ unsigned short sb[CHUNK];
    for (int i = threadIdx.x; i < nb; i += RB) hist[i] = 0u;
    __syncthreads();
    long base0 = (long)blockIdx.x * CHUNK;
    #pragma unroll
    for (int k = 0; k < CHUNK / RB; k++) {
        int li = k * RB + threadIdx.x;
        long e = base0 + li;
        if (e < E) {
            unsigned s = (unsigned)src[e], d = (unsigned)dst[e];
            unsigned b = d >> W_SHIFT, loc = d & (W - 1);
            sval[li] = s | (loc << 20);
            sb[li] = (unsigned short)b;
            atomicAdd(&hist[b], 1u);
        } else {
            sb[li] = 0xFFFFu;
        }
    }
    __syncthreads();
    for (int b = threadIdx.x; b < nb; b += RB) {
        unsigned c = hist[b];
        if (c) hist[b] = atomicAdd(&fill[b], c);  // hist[b] becomes running ptr
    }
    __syncthreads();
    #pragma unroll
    for (int k = 0; k < CHUNK / RB; k++) {
        int li = k * RB + threadIdx.x;
        unsigned b = sb[li];
        if (b != 0xFFFFu) {
            unsigned idx = atomicAdd(&hist[b], 1u);
            perm[idx] = sval[li];
        }
    }
}

__global__ __launch_bounds__(AB) void k_dinv(const unsigned* __restrict__ perm,
                                             const unsigned* __restrict__ base,
                                             float* __restrict__ dinv, int N) {
    __shared__ unsigned c[W];
    for (int i = threadIdx.x; i < W; i += AB) c[i] = 0u;
    __syncthreads();
    int b = blockIdx.x;
    unsigned s = base[b], e = base[b + 1];
    for (unsigned i = s + threadIdx.x; i < e; i += AB)
        atomicAdd(&c[perm[i] >> 20], 1u);
    __syncthreads();
    int d0 = b << W_SHIFT;
    for (int l = threadIdx.x; l < W; l += AB) {
        int d = d0 + l;
        if (d < N) dinv[d] = rsqrtf((float)(c[l] + 1u));  // +1 self-loop
    }
}

__global__ __launch_bounds__(256) void k_node1(const float2* __restrict__ x,
                                               const float* __restrict__ W1,
                                               const float* __restrict__ dinv,
                                               float4* __restrict__ h1s, int n) {
    int i = blockIdx.x * 256 + threadIdx.x;
    if (i >= n) return;
    float dv = dinv[i];
    float2 xv = x[i];
    float4 h;
    h.x = fmaf(xv.y, W1[4], xv.x * W1[0]) * dv;
    h.y = fmaf(xv.y, W1[5], xv.x * W1[1]) * dv;
    h.z = fmaf(xv.y, W1[6], xv.x * W1[2]) * dv;
    h.w = fmaf(xv.y, W1[7], xv.x * W1[3]) * dv;
    h1s[i] = h;
}

__global__ __launch_bounds__(AB) void k_acc1(const unsigned* __restrict__ perm,
                                             const unsigned* __restrict__ base,
                                             const float4* __restrict__ h1s,
                                             const float* __restrict__ dinv,
                                             float4* __restrict__ agg1, int N) {
    __shared__ float acc[W * 4];
    for (int i = threadIdx.x; i < W * 4; i += AB) acc[i] = 0.0f;
    __syncthreads();
    int b = blockIdx.x;
    unsigned s = base[b], e = base[b + 1];
    for (unsigned i = s + threadIdx.x; i < e; i += AB) {
        unsigned p = perm[i];
        float4 m = h1s[p & 0xFFFFFu];
        float* a = &acc[(p >> 20) * 4];
        atomicAdd(a + 0, m.x);
        atomicAdd(a + 1, m.y);
        atomicAdd(a + 2, m.z);
        atomicAdd(a + 3, m.w);
    }
    __syncthreads();
    int d0 = b << W_SHIFT;
    for (int l = threadIdx.x; l < W; l += AB) {
        int d = d0 + l;
        if (d < N) {
            float dv = dinv[d];
            float4 h = h1s[d];  // self-loop term
            float4 r;
            r.x = (acc[l * 4 + 0] + h.x) * dv;
            r.y = (acc[l * 4 + 1] + h.y) * dv;
            r.z = (acc[l * 4 + 2] + h.z) * dv;
            r.w = (acc[l * 4 + 3] + h.w) * dv;
            agg1[d] = r;
        }
    }
}

__global__ __launch_bounds__(256) void k_node2(const float4* __restrict__ agg1,
                                               const float* __restrict__ b1,
                                               const float* __restrict__ W2,
                                               const float* __restrict__ dinv,
                                               float2* __restrict__ h2s, int n) {
    int i = blockIdx.x * 256 + threadIdx.x;
    if (i >= n) return;
    float4 a = agg1[i];
    a.x = fmaxf(a.x + b1[0], 0.0f);
    a.y = fmaxf(a.y + b1[1], 0.0f);
    a.z = fmaxf(a.z + b1[2], 0.0f);
    a.w = fmaxf(a.w + b1[3], 0.0f);
    float dv = dinv[i];
    float2 h;
    h.x = (a.x * W2[0] + a.y * W2[2] + a.z * W2[4] + a.w * W2[6]) * dv;
    h.y = (a.x * W2[1] + a.y * W2[3] + a.z * W2[5] + a.w * W2[7]) * dv;
    h2s[i] = h;
}

__global__ __launch_bounds__(AB) void k_acc2(const unsigned* __restrict__ perm,
                                             const unsigned* __restrict__ base,
                                             const float2* __restrict__ h2s,
                                             const float* __restrict__ dinv,
                                             const float* __restrict__ b2,
                                             float2* __restrict__ out, int N) {
    __shared__ float acc[W * 2];
    for (int i = threadIdx.x; i < W * 2; i += AB) acc[i] = 0.0f;
    __syncthreads();
    int b = blockIdx.x;
    unsigned s = base[b], e = base[b + 1];
    for (unsigned i = s + threadIdx.x; i < e; i += AB) {
        unsigned p = perm[i];
        float2 m = h2s[p & 0xFFFFFu];
        float* a = &acc[(p >> 20) * 2];
        atomicAdd(a + 0, m.x);
        atomicAdd(a + 1, m.y);
    }
    __syncthreads();
    int d0 = b << W_SHIFT;
    float bb0 = b2[0], bb1 = b2[1];
    for (int l = threadIdx.x; l < W; l += AB) {
        int d = d0 + l;
        if (d < N) {
            float dv = dinv[d];
            float2 h = h2s[d];  // self-loop term
            out[d] = make_float2((acc[l * 2 + 0] + h.x) * dv + bb0,
                                 (acc[l * 2 + 1] + h.y) * dv + bb1);
        }
    }
}

// ---------------- fallback (R1) kernels ----------------

__global__ __launch_bounds__(256) void f_init_deg(unsigned* deg, int n) {
    int i = blockIdx.x * 256 + threadIdx.x;
    if (i < n) deg[i] = 1u;
}
__global__ __launch_bounds__(256) void f_count_deg(const int* dst, unsigned* deg, int E) {
    int e = blockIdx.x * 256 + threadIdx.x;
    if (e < E) atomicAdd(&deg[dst[e]], 1u);
}
__global__ __launch_bounds__(256) void f_node1(const float2* x, const float* W1,
                                               const unsigned* deg, float* dinv,
                                               float4* h1s, float4* agg1, int n) {
    int i = blockIdx.x * 256 + threadIdx.x;
    if (i >= n) return;
    float dv = rsqrtf((float)deg[i]);
    dinv[i] = dv;
    float2 xv = x[i];
    float4 h;
    h.x = fmaf(xv.y, W1[4], xv.x * W1[0]) * dv;
    h.y = fmaf(xv.y, W1[5], xv.x * W1[1]) * dv;
    h.z = fmaf(xv.y, W1[6], xv.x * W1[2]) * dv;
    h.w = fmaf(xv.y, W1[7], xv.x * W1[3]) * dv;
    h1s[i] = h;
    agg1[i] = make_float4(h.x * dv, h.y * dv, h.z * dv, h.w * dv);
}
__global__ __launch_bounds__(256) void f_edge1(const int* src, const int* dst,
                                               const float* dinv, const float4* h1s,
                                               float* agg1, int E) {
    int e = blockIdx.x * 256 + threadIdx.x;
    if (e >= E) return;
    int s = src[e], d = dst[e];
    float w = dinv[d];
    float4 m = h1s[s];
    float* p = agg1 + 4ll * d;
    unsafeAtomicAdd(p + 0, m.x * w);
    unsafeAtomicAdd(p + 1, m.y * w);
    unsafeAtomicAdd(p + 2, m.z * w);
    unsafeAtomicAdd(p + 3, m.w * w);
}
__global__ __launch_bounds__(256) void f_node2(const float4* agg1, const float* b1,
                                               const float* W2, const float* b2,
                                               const float* dinv, float2* h2s,
                                               float2* out, int n) {
    int i = blockIdx.x * 256 + threadIdx.x;
    if (i >= n) return;
    float4 a = agg1[i];
    a.x = fmaxf(a.x + b1[0], 0.0f);
    a.y = fmaxf(a.y + b1[1], 0.0f);
    a.z = fmaxf(a.z + b1[2], 0.0f);
    a.w = fmaxf(a.w + b1[3], 0.0f);
    float dv = dinv[i];
    float2 h;
    h.x = (a.x * W2[0] + a.y * W2[2] + a.z * W2[4] + a.w * W2[6]) * dv;
    h.y = (a.x * W2[1] + a.y * W2[3] + a.z * W2[5] + a.w * W2[7]) * dv;
    h2s[i] = h;
    out[i] = make_float2(b2[0] + h.x * dv, b2[1] + h.y * dv);
}
__global__ __launch_bounds__(256) void f_edge2(const int* src, const int* dst,
                                               const float* dinv, const float2* h2s,
                                               float* out, int E) {
    int e = blockIdx.x * 256 + threadIdx.x;
    if (e >= E) return;
    int s = src[e], d = dst[e];
    float w = dinv[d];
    float2 m = h2s[s];
    float* p = out + 2ll * d;
    unsafeAtomicAdd(p + 0, m.x * w);
    unsafeAtomicAdd(p + 1, m.y * w);
}

extern "C" void kernel_launch(void* const* d_in, const int* in_sizes, int n_in,
                              void* d_out, int out_size, void* d_ws, size_t ws_size,
                              hipStream_t stream) {
    const float* x  = (const float*)d_in[0];
    const int* ei   = (const int*)d_in[1];   // [2, E] int32 per harness contract
    const float* W1 = (const float*)d_in[2];
    const float* b1 = (const float*)d_in[3];
    const float* W2 = (const float*)d_in[4];
    const float* b2 = (const float*)d_in[5];
    float* out = (float*)d_out;

    const int N = in_sizes[0] / 2;
    const int E = in_sizes[1] / 2;
    const int* src = ei;
    const int* dst = ei + E;
    const int NB = (N + W - 1) >> W_SHIFT;

    char* ws = (char*)d_ws;
    const int gN = (N + 255) / 256;
    const int gE = (E + 255) / 256;

    // fast-path workspace: counters(32KB) | dinv 4N | h1s 16N | agg1 16N | perm 4E
    size_t need = 32768 + (size_t)36 * N + (size_t)4 * E;
    bool fast = (ws_size >= need) && (NB <= MAXB) && (N <= (1 << 20)) && (W <= 1024);

    if (fast) {
        unsigned* bucket_cnt  = (unsigned*)(ws);
        unsigned* bucket_base = (unsigned*)(ws + 8192);
        unsigned* bucket_fill = (unsigned*)(ws + 16384);
        float*    dinv = (float*)(ws + 32768);
        float*    h1s  = (float*)(ws + 32768 + (size_t)4 * N);
        float*    agg1 = (float*)(ws + 32768 + (size_t)20 * N);
        unsigned* perm = (unsigned*)(ws + 32768 + (size_t)36 * N);
        float*    h2s  = h1s;  // h1s dead after k_acc1... (still used for self term inside k_acc1; reuse after)

        k_zero<<<(NB + 255) / 256, 256, 0, stream>>>(bucket_cnt, NB);
        k_hist<<<2048, 256, 0, stream>>>(dst, bucket_cnt, E, NB);
        k_scan<<<1, 1024, 0, stream>>>(bucket_cnt, bucket_base, bucket_fill, NB);
        k_reorder<<<(E + CHUNK - 1) / CHUNK, RB, 0, stream>>>(src, dst, bucket_fill, perm, E, NB);
        k_dinv<<<NB, AB, 0, stream>>>(perm, bucket_base, dinv, N);
        k_node1<<<gN, 256, 0, stream>>>((const float2*)x, W1, dinv, (float4*)h1s, N);
        k_acc1<<<NB, AB, 0, stream>>>(perm, bucket_base, (const float4*)h1s, dinv,
                                      (float4*)agg1, N);
        k_node2<<<gN, 256, 0, stream>>>((const float4*)agg1, b1, W2, dinv, (float2*)h2s, N);
        k_acc2<<<NB, AB, 0, stream>>>(perm, bucket_base, (const float2*)h2s, dinv, b2,
                                      (float2*)out, N);
    } else {
        unsigned* deg = (unsigned*)(ws);
        float* dinv   = (float*)(ws + (size_t)4 * N);
        float* h1s    = (float*)(ws + (size_t)8 * N);
        float* agg1   = (float*)(ws + (size_t)24 * N);
        float* h2s    = h1s;

        f_init_deg<<<gN, 256, 0, stream>>>(deg, N);
        f_count_deg<<<gE, 256, 0, stream>>>(dst, deg, E);
        f_node1<<<gN, 256, 0, stream>>>((const float2*)x, W1, deg, dinv,
                                        (float4*)h1s, (float4*)agg1, N);
        f_edge1<<<gE, 256, 0, stream>>>(src, dst, dinv, (const float4*)h1s, agg1, E);
        f_node2<<<gN, 256, 0, stream>>>((const float4*)agg1, b1, W2, b2, dinv,
                                        (float2*)h2s, (float2*)out, N);
        f_edge2<<<gE, 256, 0, stream>>>(src, dst, dinv, (const float2*)h2s, out, E);
    }
}

// Round 3
// 895.830 us; speedup vs baseline: 6.0885x; 1.0471x over previous
//
#include <hip/hip_runtime.h>
#include <hip/hip_fp16.h>

// GCN 2-layer forward, MI355X. R3: L2-resident fp16 gather tables.
// vs R2: the acc kernels gathered 16B/8B fp32 node features from 16MB/8MB
// tables -> ~1GB of 64B-line L2-miss traffic each. Now both layers gather a
// 4MB half2 table (xs = x*dinv for layer1, h2s = h2*dinv for layer2) which
// replicates into each XCD's 4MB L2; layer-1 messages (x@W1) are computed
// per-edge in registers (VALU was 0.85% busy). Edge loops unrolled x4 for MLP.
//
// Pipeline:
//   zero/hist/scan/reorder : counting-sort edges into 1024-node dst windows,
//                            perm[p] = src(20b) | dst_local(10b)<<20
//   dinv  : per-window LDS degree count -> dinv = 1/sqrt(deg+1)
//   node1 : xs[i] = half2(x[i]*dinv[i])                      (4MB table)
//   acc1  : LDS-accumulate (xs[src]@W1); agg1[d]=dinv[d]*(sum+self)
//   node2 : h2s[i] = half2((relu(agg1+b1)@W2)*dinv[i])       (4MB table)
//   acc2  : LDS-accumulate h2s[src]; out[d]=dinv[d]*(sum+self)+b2
// Workspace: 32KB counters | dinv 4N | xs 4N | agg1 16N | h2s 4N | perm 4E.

constexpr int W_SHIFT = 10;
constexpr int W = 1024;            // nodes per dst window
constexpr int MAXB = 1024;         // max buckets
constexpr int RB = 512;            // reorder block threads
constexpr int CHUNK = 8192;        // edges per reorder block
constexpr int AB = 512;            // accumulate block threads

__global__ __launch_bounds__(256) void k_zero(unsigned* __restrict__ cnt, int nb) {
    int i = blockIdx.x * 256 + threadIdx.x;
    if (i < nb) cnt[i] = 0u;
}

__global__ __launch_bounds__(256) void k_hist(const int* __restrict__ dst,
                                              unsigned* __restrict__ cnt, int E, int nb) {
    __shared__ unsigned h[MAXB];
    for (int i = threadIdx.x; i < nb; i += 256) h[i] = 0u;
    __syncthreads();
    for (long e = blockIdx.x * 256l + threadIdx.x; e < E; e += (long)gridDim.x * 256)
        atomicAdd(&h[((unsigned)dst[e]) >> W_SHIFT], 1u);
    __syncthreads();
    for (int i = threadIdx.x; i < nb; i += 256) {
        unsigned v = h[i];
        if (v) atomicAdd(&cnt[i], v);
    }
}

__global__ __launch_bounds__(1024) void k_scan(const unsigned* __restrict__ cnt,
                                               unsigned* __restrict__ base,
                                               unsigned* __restrict__ fill, int nb) {
    __shared__ unsigned s[1024];
    int t = threadIdx.x;
    unsigned v = (t < nb) ? cnt[t] : 0u;
    s[t] = v;
    __syncthreads();
    for (int off = 1; off < 1024; off <<= 1) {
        unsigned u = (t >= off) ? s[t - off] : 0u;
        __syncthreads();
        s[t] += u;
        __syncthreads();
    }
    unsigned ex = s[t] - v;
    if (t < nb) { base[t] = ex; fill[t] = ex; }
    if (t == 1023) base[nb] = s[1023];
}

__global__ __launch_bounds__(RB) void k_reorder(const int* __restrict__ src,
                                                const int* __restrict__ dst,
                                                unsigned* __restrict__ fill,
                                                unsigned* __restrict__ perm,
                                                int E, int nb) {
    __shared__ unsigned hist[MAXB];
    __shared__ unsigned sval[CHUNK];
    __shared__ unsigned short sb[CHUNK];
    for (int i = threadIdx.x; i < nb; i += RB) hist[i] = 0u;
    __syncthreads();
    long base0 = (long)blockIdx.x * CHUNK;
    #pragma unroll
    for (int k = 0; k < CHUNK / RB; k++) {
        int li = k * RB + threadIdx.x;
        long e = base0 + li;
        if (e < E) {
            unsigned s = (unsigned)src[e], d = (unsigned)dst[e];
            unsigned b = d >> W_SHIFT, loc = d & (W - 1);
            sval[li] = s | (loc << 20);
            sb[li] = (unsigned short)b;
            atomicAdd(&hist[b], 1u);
        } else {
            sb[li] = 0xFFFFu;
        }
    }
    __syncthreads();
    for (int b = threadIdx.x; b < nb; b += RB) {
        unsigned c = hist[b];
        if (c) hist[b] = atomicAdd(&fill[b], c);  // hist[b] -> running write ptr
    }
    __syncthreads();
    #pragma unroll
    for (int k = 0; k < CHUNK / RB; k++) {
        int li = k * RB + threadIdx.x;
        unsigned b = sb[li];
        if (b != 0xFFFFu) {
            unsigned idx = atomicAdd(&hist[b], 1u);
            perm[idx] = sval[li];
        }
    }
}

__global__ __launch_bounds__(AB) void k_dinv(const unsigned* __restrict__ perm,
                                             const unsigned* __restrict__ base,
                                             float* __restrict__ dinv, int N) {
    __shared__ unsigned c[W];
    for (int i = threadIdx.x; i < W; i += AB) c[i] = 0u;
    __syncthreads();
    int b = blockIdx.x;
    unsigned s = base[b], e = base[b + 1];
    for (unsigned i = s + threadIdx.x; i < e; i += AB)
        atomicAdd(&c[perm[i] >> 20], 1u);
    __syncthreads();
    int d0 = b << W_SHIFT;
    for (int l = threadIdx.x; l < W; l += AB) {
        int d = d0 + l;
        if (d < N) dinv[d] = 1.0f / sqrtf((float)(c[l] + 1u));  // +1 self-loop
    }
}

__global__ __launch_bounds__(256) void k_node1(const float2* __restrict__ x,
                                               const float* __restrict__ dinv,
                                               __half2* __restrict__ xs, int n) {
    int i = blockIdx.x * 256 + threadIdx.x;
    if (i >= n) return;
    float dv = dinv[i];
    float2 xv = x[i];
    xs[i] = __floats2half2_rn(xv.x * dv, xv.y * dv);
}

__global__ __launch_bounds__(AB) void k_acc1(const unsigned* __restrict__ perm,
                                             const unsigned* __restrict__ base,
                                             const __half2* __restrict__ xs,
                                             const float* __restrict__ dinv,
                                             const float* __restrict__ W1,
                                             float4* __restrict__ agg1, int N) {
    __shared__ float acc[W * 4];
    float w00 = W1[0], w01 = W1[1], w02 = W1[2], w03 = W1[3];
    float w10 = W1[4], w11 = W1[5], w12 = W1[6], w13 = W1[7];
    for (int i = threadIdx.x; i < W * 4; i += AB) acc[i] = 0.0f;
    __syncthreads();
    int b = blockIdx.x;
    unsigned s = base[b], e = base[b + 1];
    unsigned i = s + threadIdx.x;
    for (; i + 3u * AB < e; i += 4u * AB) {
        unsigned p0 = perm[i], p1 = perm[i + AB], p2 = perm[i + 2u * AB], p3 = perm[i + 3u * AB];
        float2 v0 = __half22float2(xs[p0 & 0xFFFFFu]);
        float2 v1 = __half22float2(xs[p1 & 0xFFFFFu]);
        float2 v2 = __half22float2(xs[p2 & 0xFFFFFu]);
        float2 v3 = __half22float2(xs[p3 & 0xFFFFFu]);
        float* a0 = &acc[(p0 >> 20) * 4];
        atomicAdd(a0 + 0, fmaf(v0.y, w10, v0.x * w00));
        atomicAdd(a0 + 1, fmaf(v0.y, w11, v0.x * w01));
        atomicAdd(a0 + 2, fmaf(v0.y, w12, v0.x * w02));
        atomicAdd(a0 + 3, fmaf(v0.y, w13, v0.x * w03));
        float* a1 = &acc[(p1 >> 20) * 4];
        atomicAdd(a1 + 0, fmaf(v1.y, w10, v1.x * w00));
        atomicAdd(a1 + 1, fmaf(v1.y, w11, v1.x * w01));
        atomicAdd(a1 + 2, fmaf(v1.y, w12, v1.x * w02));
        atomicAdd(a1 + 3, fmaf(v1.y, w13, v1.x * w03));
        float* a2 = &acc[(p2 >> 20) * 4];
        atomicAdd(a2 + 0, fmaf(v2.y, w10, v2.x * w00));
        atomicAdd(a2 + 1, fmaf(v2.y, w11, v2.x * w01));
        atomicAdd(a2 + 2, fmaf(v2.y, w12, v2.x * w02));
        atomicAdd(a2 + 3, fmaf(v2.y, w13, v2.x * w03));
        float* a3 = &acc[(p3 >> 20) * 4];
        atomicAdd(a3 + 0, fmaf(v3.y, w10, v3.x * w00));
        atomicAdd(a3 + 1, fmaf(v3.y, w11, v3.x * w01));
        atomicAdd(a3 + 2, fmaf(v3.y, w12, v3.x * w02));
        atomicAdd(a3 + 3, fmaf(v3.y, w13, v3.x * w03));
    }
    for (; i < e; i += AB) {
        unsigned p = perm[i];
        float2 v = __half22float2(xs[p & 0xFFFFFu]);
        float* a = &acc[(p >> 20) * 4];
        atomicAdd(a + 0, fmaf(v.y, w10, v.x * w00));
        atomicAdd(a + 1, fmaf(v.y, w11, v.x * w01));
        atomicAdd(a + 2, fmaf(v.y, w12, v.x * w02));
        atomicAdd(a + 3, fmaf(v.y, w13, v.x * w03));
    }
    __syncthreads();
    int d0 = b << W_SHIFT;
    for (int l = threadIdx.x; l < W; l += AB) {
        int d = d0 + l;
        if (d < N) {
            float dv = dinv[d];
            float2 v = __half22float2(xs[d]);  // self-loop message
            float4 r;
            r.x = (acc[l * 4 + 0] + fmaf(v.y, w10, v.x * w00)) * dv;
            r.y = (acc[l * 4 + 1] + fmaf(v.y, w11, v.x * w01)) * dv;
            r.z = (acc[l * 4 + 2] + fmaf(v.y, w12, v.x * w02)) * dv;
            r.w = (acc[l * 4 + 3] + fmaf(v.y, w13, v.x * w03)) * dv;
            agg1[d] = r;
        }
    }
}

__global__ __launch_bounds__(256) void k_node2(const float4* __restrict__ agg1,
                                               const float* __restrict__ b1,
                                               const float* __restrict__ W2,
                                               const float* __restrict__ dinv,
                                               __half2* __restrict__ h2s, int n) {
    int i = blockIdx.x * 256 + threadIdx.x;
    if (i >= n) return;
    float4 a = agg1[i];
    a.x = fmaxf(a.x + b1[0], 0.0f);
    a.y = fmaxf(a.y + b1[1], 0.0f);
    a.z = fmaxf(a.z + b1[2], 0.0f);
    a.w = fmaxf(a.w + b1[3], 0.0f);
    float dv = dinv[i];
    float hx = (a.x * W2[0] + a.y * W2[2] + a.z * W2[4] + a.w * W2[6]) * dv;
    float hy = (a.x * W2[1] + a.y * W2[3] + a.z * W2[5] + a.w * W2[7]) * dv;
    h2s[i] = __floats2half2_rn(hx, hy);
}

__global__ __launch_bounds__(AB) void k_acc2(const unsigned* __restrict__ perm,
                                             const unsigned* __restrict__ base,
                                             const __half2* __restrict__ h2s,
                                             const float* __restrict__ dinv,
                                             const float* __restrict__ b2,
                                             float2* __restrict__ out, int N) {
    __shared__ float acc[W * 2];
    for (int i = threadIdx.x; i < W * 2; i += AB) acc[i] = 0.0f;
    __syncthreads();
    int b = blockIdx.x;
    unsigned s = base[b], e = base[b + 1];
    unsigned i = s + threadIdx.x;
    for (; i + 3u * AB < e; i += 4u * AB) {
        unsigned p0 = perm[i], p1 = perm[i + AB], p2 = perm[i + 2u * AB], p3 = perm[i + 3u * AB];
        float2 v0 = __half22float2(h2s[p0 & 0xFFFFFu]);
        float2 v1 = __half22float2(h2s[p1 & 0xFFFFFu]);
        float2 v2 = __half22float2(h2s[p2 & 0xFFFFFu]);
        float2 v3 = __half22float2(h2s[p3 & 0xFFFFFu]);
        float* a0 = &acc[(p0 >> 20) * 2];
        atomicAdd(a0 + 0, v0.x); atomicAdd(a0 + 1, v0.y);
        float* a1 = &acc[(p1 >> 20) * 2];
        atomicAdd(a1 + 0, v1.x); atomicAdd(a1 + 1, v1.y);
        float* a2 = &acc[(p2 >> 20) * 2];
        atomicAdd(a2 + 0, v2.x); atomicAdd(a2 + 1, v2.y);
        float* a3 = &acc[(p3 >> 20) * 2];
        atomicAdd(a3 + 0, v3.x); atomicAdd(a3 + 1, v3.y);
    }
    for (; i < e; i += AB) {
        unsigned p = perm[i];
        float2 v = __half22float2(h2s[p & 0xFFFFFu]);
        float* a = &acc[(p >> 20) * 2];
        atomicAdd(a + 0, v.x); atomicAdd(a + 1, v.y);
    }
    __syncthreads();
    int d0 = b << W_SHIFT;
    float bb0 = b2[0], bb1 = b2[1];
    for (int l = threadIdx.x; l < W; l += AB) {
        int d = d0 + l;
        if (d < N) {
            float dv = dinv[d];
            float2 v = __half22float2(h2s[d]);  // self-loop message
            out[d] = make_float2((acc[l * 2 + 0] + v.x) * dv + bb0,
                                 (acc[l * 2 + 1] + v.y) * dv + bb1);
        }
    }
}

// ---------------- fallback (R1-style) ----------------

__global__ __launch_bounds__(256) void f_init_deg(unsigned* deg, int n) {
    int i = blockIdx.x * 256 + threadIdx.x;
    if (i < n) deg[i] = 1u;
}
__global__ __launch_bounds__(256) void f_count_deg(const int* dst, unsigned* deg, int E) {
    int e = blockIdx.x * 256 + threadIdx.x;
    if (e < E) atomicAdd(&deg[dst[e]], 1u);
}
__global__ __launch_bounds__(256) void f_node1(const float2* x, const float* W1,
                                               const unsigned* deg, float* dinv,
                                               float4* h1s, float4* agg1, int n) {
    int i = blockIdx.x * 256 + threadIdx.x;
    if (i >= n) return;
    float dv = 1.0f / sqrtf((float)deg[i]);
    dinv[i] = dv;
    float2 xv = x[i];
    float4 h;
    h.x = fmaf(xv.y, W1[4], xv.x * W1[0]) * dv;
    h.y = fmaf(xv.y, W1[5], xv.x * W1[1]) * dv;
    h.z = fmaf(xv.y, W1[6], xv.x * W1[2]) * dv;
    h.w = fmaf(xv.y, W1[7], xv.x * W1[3]) * dv;
    h1s[i] = h;
    agg1[i] = make_float4(h.x * dv, h.y * dv, h.z * dv, h.w * dv);
}
__global__ __launch_bounds__(256) void f_edge1(const int* src, const int* dst,
                                               const float* dinv, const float4* h1s,
                                               float* agg1, int E) {
    int e = blockIdx.x * 256 + threadIdx.x;
    if (e >= E) return;
    int s = src[e], d = dst[e];
    float w = dinv[d];
    float4 m = h1s[s];
    float* p = agg1 + 4ll * d;
    unsafeAtomicAdd(p + 0, m.x * w);
    unsafeAtomicAdd(p + 1, m.y * w);
    unsafeAtomicAdd(p + 2, m.z * w);
    unsafeAtomicAdd(p + 3, m.w * w);
}
__global__ __launch_bounds__(256) void f_node2(const float4* agg1, const float* b1,
                                               const float* W2, const float* b2,
                                               const float* dinv, float2* h2s,
                                               float2* out, int n) {
    int i = blockIdx.x * 256 + threadIdx.x;
    if (i >= n) return;
    float4 a = agg1[i];
    a.x = fmaxf(a.x + b1[0], 0.0f);
    a.y = fmaxf(a.y + b1[1], 0.0f);
    a.z = fmaxf(a.z + b1[2], 0.0f);
    a.w = fmaxf(a.w + b1[3], 0.0f);
    float dv = dinv[i];
    float2 h;
    h.x = (a.x * W2[0] + a.y * W2[2] + a.z * W2[4] + a.w * W2[6]) * dv;
    h.y = (a.x * W2[1] + a.y * W2[3] + a.z * W2[5] + a.w * W2[7]) * dv;
    h2s[i] = h;
    out[i] = make_float2(b2[0] + h.x * dv, b2[1] + h.y * dv);
}
__global__ __launch_bounds__(256) void f_edge2(const int* src, const int* dst,
                                               const float* dinv, const float2* h2s,
                                               float* out, int E) {
    int e = blockIdx.x * 256 + threadIdx.x;
    if (e >= E) return;
    int s = src[e], d = dst[e];
    float w = dinv[d];
    float2 m = h2s[s];
    float* p = out + 2ll * d;
    unsafeAtomicAdd(p + 0, m.x * w);
    unsafeAtomicAdd(p + 1, m.y * w);
}

extern "C" void kernel_launch(void* const* d_in, const int* in_sizes, int n_in,
                              void* d_out, int out_size, void* d_ws, size_t ws_size,
                              hipStream_t stream) {
    const float* x  = (const float*)d_in[0];
    const int* ei   = (const int*)d_in[1];
    const float* W1 = (const float*)d_in[2];
    const float* b1 = (const float*)d_in[3];
    const float* W2 = (const float*)d_in[4];
    const float* b2 = (const float*)d_in[5];
    float* out = (float*)d_out;

    const int N = in_sizes[0] / 2;
    const int E = in_sizes[1] / 2;
    const int* src = ei;
    const int* dst = ei + E;
    const int NB = (N + W - 1) >> W_SHIFT;

    char* ws = (char*)d_ws;
    const int gN = (N + 255) / 256;
    const int gE = (E + 255) / 256;

    // fast ws: counters 32KB | dinv 4N | xs 4N | agg1 16N | h2s 4N | perm 4E
    size_t need = 32768 + (size_t)28 * N + (size_t)4 * E;
    bool fast = (ws_size >= need) && (NB <= MAXB) && (N <= (1 << 20));

    if (fast) {
        unsigned* bucket_cnt  = (unsigned*)(ws);
        unsigned* bucket_base = (unsigned*)(ws + 8192);
        unsigned* bucket_fill = (unsigned*)(ws + 16384);
        float*    dinv = (float*)(ws + 32768);
        __half2*  xs   = (__half2*)(ws + 32768 + (size_t)4 * N);
        float*    agg1 = (float*)(ws + 32768 + (size_t)8 * N);
        __half2*  h2s  = (__half2*)(ws + 32768 + (size_t)24 * N);
        unsigned* perm = (unsigned*)(ws + 32768 + (size_t)28 * N);

        k_zero<<<(NB + 255) / 256, 256, 0, stream>>>(bucket_cnt, NB);
        k_hist<<<2048, 256, 0, stream>>>(dst, bucket_cnt, E, NB);
        k_scan<<<1, 1024, 0, stream>>>(bucket_cnt, bucket_base, bucket_fill, NB);
        k_reorder<<<(E + CHUNK - 1) / CHUNK, RB, 0, stream>>>(src, dst, bucket_fill, perm, E, NB);
        k_dinv<<<NB, AB, 0, stream>>>(perm, bucket_base, dinv, N);
        k_node1<<<gN, 256, 0, stream>>>((const float2*)x, dinv, xs, N);
        k_acc1<<<NB, AB, 0, stream>>>(perm, bucket_base, xs, dinv, W1, (float4*)agg1, N);
        k_node2<<<gN, 256, 0, stream>>>((const float4*)agg1, b1, W2, dinv, h2s, N);
        k_acc2<<<NB, AB, 0, stream>>>(perm, bucket_base, h2s, dinv, b2, (float2*)out, N);
    } else {
        unsigned* deg = (unsigned*)(ws);
        float* dinv   = (float*)(ws + (size_t)4 * N);
        float* h1s    = (float*)(ws + (size_t)8 * N);
        float* agg1   = (float*)(ws + (size_t)24 * N);
        float* h2s    = h1s;

        f_init_deg<<<gN, 256, 0, stream>>>(deg, N);
        f_count_deg<<<gE, 256, 0, stream>>>(dst, deg, E);
        f_node1<<<gN, 256, 0, stream>>>((const float2*)x, W1, deg, dinv,
                                        (float4*)h1s, (float4*)agg1, N);
        f_edge1<<<gE, 256, 0, stream>>>(src, dst, dinv, (const float4*)h1s, agg1, E);
        f_node2<<<gN, 256, 0, stream>>>((const float4*)agg1, b1, W2, b2, dinv,
                                        (float2*)h2s, (float2*)out, N);
        f_edge2<<<gE, 256, 0, stream>>>(src, dst, dinv, (const float2*)h2s, out, E);
    }
}

// Round 4
// 725.673 us; speedup vs baseline: 7.5162x; 1.2345x over previous
//
#include <hip/hip_runtime.h>
#include <hip/hip_fp16.h>

// GCN 2-layer forward, MI355X. R4: linearity + LDS bank spread + fusion.
// vs R3 (k_acc1 347us, time invariant to HBM traffic => LDS-atomic /
// transaction bound, not bandwidth bound):
//  - layer1 accumulates the RAW 2-comp xs (2 LDS atomics/edge, was 4);
//    W1 is applied once per node at flush (aggregation is linear).
//  - LDS accumulator stride padded 2->3 floats: (3l+c)%32 covers all 32
//    banks (stride-4 covered only 8 -> built-in 8-way atomic conflict).
//  - acc1 flush fuses the entire node MLP (relu(.+b1)@W2*dinv) -> writes
//    h2s directly; k_node2 and the 32MB agg1 round-trip are gone.
//  - k_node1 fused into k_dinv flush (xs = half2(x*dinv)).
//  - perm is read with non-temporal loads so the 64MB stream doesn't evict
//    the 4MB half2 gather table from per-XCD L2.
// Pipeline: zero, hist, scan, reorder, dinv(+node1), acc1(+node2), acc2.
// Workspace: 32KB counters | dinv 4N | xs 4N | h2s 4N | perm 4E  (~76MB).

constexpr int W_SHIFT = 10;
constexpr int W = 1024;            // nodes per dst window
constexpr int MAXB = 1024;         // max buckets
constexpr int RB = 512;            // reorder block threads
constexpr int CHUNK = 8192;        // edges per reorder block
constexpr int AB = 512;            // accumulate block threads
constexpr int PAD = 3;             // LDS accumulator stride (floats), coprime to 32

__global__ __launch_bounds__(256) void k_zero(unsigned* __restrict__ cnt, int nb) {
    int i = blockIdx.x * 256 + threadIdx.x;
    if (i < nb) cnt[i] = 0u;
}

__global__ __launch_bounds__(256) void k_hist(const int* __restrict__ dst,
                                              unsigned* __restrict__ cnt, int E, int nb) {
    __shared__ unsigned h[MAXB];
    for (int i = threadIdx.x; i < nb; i += 256) h[i] = 0u;
    __syncthreads();
    for (long e = blockIdx.x * 256l + threadIdx.x; e < E; e += (long)gridDim.x * 256)
        atomicAdd(&h[((unsigned)dst[e]) >> W_SHIFT], 1u);
    __syncthreads();
    for (int i = threadIdx.x; i < nb; i += 256) {
        unsigned v = h[i];
        if (v) atomicAdd(&cnt[i], v);
    }
}

__global__ __launch_bounds__(1024) void k_scan(const unsigned* __restrict__ cnt,
                                               unsigned* __restrict__ base,
                                               unsigned* __restrict__ fill, int nb) {
    __shared__ unsigned s[1024];
    int t = threadIdx.x;
    unsigned v = (t < nb) ? cnt[t] : 0u;
    s[t] = v;
    __syncthreads();
    for (int off = 1; off < 1024; off <<= 1) {
        unsigned u = (t >= off) ? s[t - off] : 0u;
        __syncthreads();
        s[t] += u;
        __syncthreads();
    }
    unsigned ex = s[t] - v;
    if (t < nb) { base[t] = ex; fill[t] = ex; }
    if (t == 1023) base[nb] = s[1023];
}

__global__ __launch_bounds__(RB) void k_reorder(const int* __restrict__ src,
                                                const int* __restrict__ dst,
                                                unsigned* __restrict__ fill,
                                                unsigned* __restrict__ perm,
                                                int E, int nb) {
    __shared__ unsigned hist[MAXB];
    __shared__ unsigned sval[CHUNK];
    __shared__ unsigned short sb[CHUNK];
    for (int i = threadIdx.x; i < nb; i += RB) hist[i] = 0u;
    __syncthreads();
    long base0 = (long)blockIdx.x * CHUNK;
    #pragma unroll
    for (int k = 0; k < CHUNK / RB; k++) {
        int li = k * RB + threadIdx.x;
        long e = base0 + li;
        if (e < E) {
            unsigned s = (unsigned)src[e], d = (unsigned)dst[e];
            unsigned b = d >> W_SHIFT, loc = d & (W - 1);
            sval[li] = s | (loc << 20);
            sb[li] = (unsigned short)b;
            atomicAdd(&hist[b], 1u);
        } else {
            sb[li] = 0xFFFFu;
        }
    }
    __syncthreads();
    for (int b = threadIdx.x; b < nb; b += RB) {
        unsigned c = hist[b];
        if (c) hist[b] = atomicAdd(&fill[b], c);  // hist[b] -> running write ptr
    }
    __syncthreads();
    #pragma unroll
    for (int k = 0; k < CHUNK / RB; k++) {
        int li = k * RB + threadIdx.x;
        unsigned b = sb[li];
        if (b != 0xFFFFu) {
            unsigned idx = atomicAdd(&hist[b], 1u);
            perm[idx] = sval[li];
        }
    }
}

// degree count + dinv + xs = half2(x*dinv), fused
__global__ __launch_bounds__(AB) void k_dinv(const unsigned* __restrict__ perm,
                                             const unsigned* __restrict__ base,
                                             const float2* __restrict__ x,
                                             float* __restrict__ dinv,
                                             __half2* __restrict__ xs, int N) {
    __shared__ unsigned c[W];
    for (int i = threadIdx.x; i < W; i += AB) c[i] = 0u;
    __syncthreads();
    int b = blockIdx.x;
    unsigned s = base[b], e = base[b + 1];
    for (unsigned i = s + threadIdx.x; i < e; i += AB)
        atomicAdd(&c[__builtin_nontemporal_load(perm + i) >> 20], 1u);
    __syncthreads();
    int d0 = b << W_SHIFT;
    for (int l = threadIdx.x; l < W; l += AB) {
        int d = d0 + l;
        if (d < N) {
            float dv = 1.0f / sqrtf((float)(c[l] + 1u));  // +1 self-loop
            dinv[d] = dv;
            float2 xv = x[d];
            xs[d] = __floats2half2_rn(xv.x * dv, xv.y * dv);
        }
    }
}

// layer1 aggregate (raw xs, 2 atomics/edge) + full node MLP at flush -> h2s
__global__ __launch_bounds__(AB) void k_acc1(const unsigned* __restrict__ perm,
                                             const unsigned* __restrict__ base,
                                             const __half2* __restrict__ xs,
                                             const float* __restrict__ dinv,
                                             const float* __restrict__ W1,
                                             const float* __restrict__ b1,
                                             const float* __restrict__ W2,
                                             __half2* __restrict__ h2s, int N) {
    __shared__ float acc[W * PAD];
    for (int i = threadIdx.x; i < W * PAD; i += AB) acc[i] = 0.0f;
    __syncthreads();
    int b = blockIdx.x;
    unsigned s = base[b], e = base[b + 1];
    unsigned i = s + threadIdx.x;
    for (; i + 3u * AB < e; i += 4u * AB) {
        unsigned p0 = __builtin_nontemporal_load(perm + i);
        unsigned p1 = __builtin_nontemporal_load(perm + i + AB);
        unsigned p2 = __builtin_nontemporal_load(perm + i + 2u * AB);
        unsigned p3 = __builtin_nontemporal_load(perm + i + 3u * AB);
        float2 v0 = __half22float2(xs[p0 & 0xFFFFFu]);
        float2 v1 = __half22float2(xs[p1 & 0xFFFFFu]);
        float2 v2 = __half22float2(xs[p2 & 0xFFFFFu]);
        float2 v3 = __half22float2(xs[p3 & 0xFFFFFu]);
        float* a0 = &acc[(p0 >> 20) * PAD];
        atomicAdd(a0 + 0, v0.x); atomicAdd(a0 + 1, v0.y);
        float* a1 = &acc[(p1 >> 20) * PAD];
        atomicAdd(a1 + 0, v1.x); atomicAdd(a1 + 1, v1.y);
        float* a2 = &acc[(p2 >> 20) * PAD];
        atomicAdd(a2 + 0, v2.x); atomicAdd(a2 + 1, v2.y);
        float* a3 = &acc[(p3 >> 20) * PAD];
        atomicAdd(a3 + 0, v3.x); atomicAdd(a3 + 1, v3.y);
    }
    for (; i < e; i += AB) {
        unsigned p = __builtin_nontemporal_load(perm + i);
        float2 v = __half22float2(xs[p & 0xFFFFFu]);
        float* a = &acc[(p >> 20) * PAD];
        atomicAdd(a + 0, v.x); atomicAdd(a + 1, v.y);
    }
    __syncthreads();
    int d0 = b << W_SHIFT;
    float w10 = W1[0], w11 = W1[1], w12 = W1[2], w13 = W1[3];
    float w14 = W1[4], w15 = W1[5], w16 = W1[6], w17 = W1[7];
    float bb0 = b1[0], bb1 = b1[1], bb2 = b1[2], bb3 = b1[3];
    float u0 = W2[0], u1 = W2[1], u2 = W2[2], u3 = W2[3];
    float u4 = W2[4], u5 = W2[5], u6 = W2[6], u7 = W2[7];
    for (int l = threadIdx.x; l < W; l += AB) {
        int d = d0 + l;
        if (d < N) {
            float dv = dinv[d];
            float2 self = __half22float2(xs[d]);
            float Sx = acc[l * PAD + 0] + self.x;
            float Sy = acc[l * PAD + 1] + self.y;
            // agg1 = (S @ W1) * dv ; a = relu(agg1 + b1)
            float a0 = fmaxf(fmaf(Sy, w14, Sx * w10) * dv + bb0, 0.0f);
            float a1 = fmaxf(fmaf(Sy, w15, Sx * w11) * dv + bb1, 0.0f);
            float a2 = fmaxf(fmaf(Sy, w16, Sx * w12) * dv + bb2, 0.0f);
            float a3 = fmaxf(fmaf(Sy, w17, Sx * w13) * dv + bb3, 0.0f);
            float hx = (a0 * u0 + a1 * u2 + a2 * u4 + a3 * u6) * dv;
            float hy = (a0 * u1 + a1 * u3 + a2 * u5 + a3 * u7) * dv;
            h2s[d] = __floats2half2_rn(hx, hy);
        }
    }
}

__global__ __launch_bounds__(AB) void k_acc2(const unsigned* __restrict__ perm,
                                             const unsigned* __restrict__ base,
                                             const __half2* __restrict__ h2s,
                                             const float* __restrict__ dinv,
                                             const float* __restrict__ b2,
                                             float2* __restrict__ out, int N) {
    __shared__ float acc[W * PAD];
    for (int i = threadIdx.x; i < W * PAD; i += AB) acc[i] = 0.0f;
    __syncthreads();
    int b = blockIdx.x;
    unsigned s = base[b], e = base[b + 1];
    unsigned i = s + threadIdx.x;
    for (; i + 3u * AB < e; i += 4u * AB) {
        unsigned p0 = __builtin_nontemporal_load(perm + i);
        unsigned p1 = __builtin_nontemporal_load(perm + i + AB);
        unsigned p2 = __builtin_nontemporal_load(perm + i + 2u * AB);
        unsigned p3 = __builtin_nontemporal_load(perm + i + 3u * AB);
        float2 v0 = __half22float2(h2s[p0 & 0xFFFFFu]);
        float2 v1 = __half22float2(h2s[p1 & 0xFFFFFu]);
        float2 v2 = __half22float2(h2s[p2 & 0xFFFFFu]);
        float2 v3 = __half22float2(h2s[p3 & 0xFFFFFu]);
        float* a0 = &acc[(p0 >> 20) * PAD];
        atomicAdd(a0 + 0, v0.x); atomicAdd(a0 + 1, v0.y);
        float* a1 = &acc[(p1 >> 20) * PAD];
        atomicAdd(a1 + 0, v1.x); atomicAdd(a1 + 1, v1.y);
        float* a2 = &acc[(p2 >> 20) * PAD];
        atomicAdd(a2 + 0, v2.x); atomicAdd(a2 + 1, v2.y);
        float* a3 = &acc[(p3 >> 20) * PAD];
        atomicAdd(a3 + 0, v3.x); atomicAdd(a3 + 1, v3.y);
    }
    for (; i < e; i += AB) {
        unsigned p = __builtin_nontemporal_load(perm + i);
        float2 v = __half22float2(h2s[p & 0xFFFFFu]);
        float* a = &acc[(p >> 20) * PAD];
        atomicAdd(a + 0, v.x); atomicAdd(a + 1, v.y);
    }
    __syncthreads();
    int d0 = b << W_SHIFT;
    float bb0 = b2[0], bb1 = b2[1];
    for (int l = threadIdx.x; l < W; l += AB) {
        int d = d0 + l;
        if (d < N) {
            float dv = dinv[d];
            float2 v = __half22float2(h2s[d]);  // self-loop message
            out[d] = make_float2((acc[l * PAD + 0] + v.x) * dv + bb0,
                                 (acc[l * PAD + 1] + v.y) * dv + bb1);
        }
    }
}

// ---------------- fallback (R1-style, only if workspace too small) ----------

__global__ __launch_bounds__(256) void f_init_deg(unsigned* deg, int n) {
    int i = blockIdx.x * 256 + threadIdx.x;
    if (i < n) deg[i] = 1u;
}
__global__ __launch_bounds__(256) void f_count_deg(const int* dst, unsigned* deg, int E) {
    int e = blockIdx.x * 256 + threadIdx.x;
    if (e < E) atomicAdd(&deg[dst[e]], 1u);
}
__global__ __launch_bounds__(256) void f_node1(const float2* x, const float* W1,
                                               const unsigned* deg, float* dinv,
                                               float4* h1s, float4* agg1, int n) {
    int i = blockIdx.x * 256 + threadIdx.x;
    if (i >= n) return;
    float dv = 1.0f / sqrtf((float)deg[i]);
    dinv[i] = dv;
    float2 xv = x[i];
    float4 h;
    h.x = fmaf(xv.y, W1[4], xv.x * W1[0]) * dv;
    h.y = fmaf(xv.y, W1[5], xv.x * W1[1]) * dv;
    h.z = fmaf(xv.y, W1[6], xv.x * W1[2]) * dv;
    h.w = fmaf(xv.y, W1[7], xv.x * W1[3]) * dv;
    h1s[i] = h;
    agg1[i] = make_float4(h.x * dv, h.y * dv, h.z * dv, h.w * dv);
}
__global__ __launch_bounds__(256) void f_edge1(const int* src, const int* dst,
                                               const float* dinv, const float4* h1s,
                                               float* agg1, int E) {
    int e = blockIdx.x * 256 + threadIdx.x;
    if (e >= E) return;
    int s = src[e], d = dst[e];
    float w = dinv[d];
    float4 m = h1s[s];
    float* p = agg1 + 4ll * d;
    unsafeAtomicAdd(p + 0, m.x * w);
    unsafeAtomicAdd(p + 1, m.y * w);
    unsafeAtomicAdd(p + 2, m.z * w);
    unsafeAtomicAdd(p + 3, m.w * w);
}
__global__ __launch_bounds__(256) void f_node2(const float4* agg1, const float* b1,
                                               const float* W2, const float* b2,
                                               const float* dinv, float2* h2s,
                                               float2* out, int n) {
    int i = blockIdx.x * 256 + threadIdx.x;
    if (i >= n) return;
    float4 a = agg1[i];
    a.x = fmaxf(a.x + b1[0], 0.0f);
    a.y = fmaxf(a.y + b1[1], 0.0f);
    a.z = fmaxf(a.z + b1[2], 0.0f);
    a.w = fmaxf(a.w + b1[3], 0.0f);
    float dv = dinv[i];
    float2 h;
    h.x = (a.x * W2[0] + a.y * W2[2] + a.z * W2[4] + a.w * W2[6]) * dv;
    h.y = (a.x * W2[1] + a.y * W2[3] + a.z * W2[5] + a.w * W2[7]) * dv;
    h2s[i] = h;
    out[i] = make_float2(b2[0] + h.x * dv, b2[1] + h.y * dv);
}
__global__ __launch_bounds__(256) void f_edge2(const int* src, const int* dst,
                                               const float* dinv, const float2* h2s,
                                               float* out, int E) {
    int e = blockIdx.x * 256 + threadIdx.x;
    if (e >= E) return;
    int s = src[e], d = dst[e];
    float w = dinv[d];
    float2 m = h2s[s];
    float* p = out + 2ll * d;
    unsafeAtomicAdd(p + 0, m.x * w);
    unsafeAtomicAdd(p + 1, m.y * w);
}

extern "C" void kernel_launch(void* const* d_in, const int* in_sizes, int n_in,
                              void* d_out, int out_size, void* d_ws, size_t ws_size,
                              hipStream_t stream) {
    const float* x  = (const float*)d_in[0];
    const int* ei   = (const int*)d_in[1];
    const float* W1 = (const float*)d_in[2];
    const float* b1 = (const float*)d_in[3];
    const float* W2 = (const float*)d_in[4];
    const float* b2 = (const float*)d_in[5];
    float* out = (float*)d_out;

    const int N = in_sizes[0] / 2;
    const int E = in_sizes[1] / 2;
    const int* src = ei;
    const int* dst = ei + E;
    const int NB = (N + W - 1) >> W_SHIFT;

    char* ws = (char*)d_ws;
    const int gN = (N + 255) / 256;
    const int gE = (E + 255) / 256;

    // fast ws: counters 32KB | dinv 4N | xs 4N | h2s 4N | perm 4E
    size_t need = 32768 + (size_t)12 * N + (size_t)4 * E;
    bool fast = (ws_size >= need) && (NB <= MAXB) && (N <= (1 << 20));

    if (fast) {
        unsigned* bucket_cnt  = (unsigned*)(ws);
        unsigned* bucket_base = (unsigned*)(ws + 8192);
        unsigned* bucket_fill = (unsigned*)(ws + 16384);
        float*    dinv = (float*)(ws + 32768);
        __half2*  xs   = (__half2*)(ws + 32768 + (size_t)4 * N);
        __half2*  h2s  = (__half2*)(ws + 32768 + (size_t)8 * N);
        unsigned* perm = (unsigned*)(ws + 32768 + (size_t)12 * N);

        k_zero<<<(NB + 255) / 256, 256, 0, stream>>>(bucket_cnt, NB);
        k_hist<<<2048, 256, 0, stream>>>(dst, bucket_cnt, E, NB);
        k_scan<<<1, 1024, 0, stream>>>(bucket_cnt, bucket_base, bucket_fill, NB);
        k_reorder<<<(E + CHUNK - 1) / CHUNK, RB, 0, stream>>>(src, dst, bucket_fill, perm, E, NB);
        k_dinv<<<NB, AB, 0, stream>>>(perm, bucket_base, (const float2*)x, dinv, xs, N);
        k_acc1<<<NB, AB, 0, stream>>>(perm, bucket_base, xs, dinv, W1, b1, W2, h2s, N);
        k_acc2<<<NB, AB, 0, stream>>>(perm, bucket_base, h2s, dinv, b2, (float2*)out, N);
    } else {
        unsigned* deg = (unsigned*)(ws);
        float* dinv   = (float*)(ws + (size_t)4 * N);
        float* h1s    = (float*)(ws + (size_t)8 * N);
        float* agg1   = (float*)(ws + (size_t)24 * N);
        float* h2s    = h1s;

        f_init_deg<<<gN, 256, 0, stream>>>(deg, N);
        f_count_deg<<<gE, 256, 0, stream>>>(dst, deg, E);
        f_node1<<<gN, 256, 0, stream>>>((const float2*)x, W1, deg, dinv,
                                        (float4*)h1s, (float4*)agg1, N);
        f_edge1<<<gE, 256, 0, stream>>>(src, dst, dinv, (const float4*)h1s, agg1, E);
        f_node2<<<gN, 256, 0, stream>>>((const float4*)agg1, b1, W2, b2, dinv,
                                        (float2*)h2s, (float2*)out, N);
        f_edge2<<<gE, 256, 0, stream>>>(src, dst, dinv, (const float2*)h2s, out, E);
    }
}

// Round 5
// 578.697 us; speedup vs baseline: 9.4251x; 1.2540x over previous
//
#include <hip/hip_runtime.h>
#include <hip/hip_fp16.h>

// GCN 2-layer forward, MI355X. R5: single-variable experiment — pack both
// accumulated feature components into ONE u64 fixed-point LDS atomic/edge
// (was two f32 atomics). Bank-touches/edge unchanged (u64 spans 2 banks),
// gather structure unchanged => discriminates atomic-instruction-rate vs
// bank/gather bottleneck models.
//   layer1: q = round(v * 2^16) + 2^20 per half  (|xs| <= ~6)
//   layer2: q = round(v * 2^12) + 2^22 per half  (|h2s| <= ~500)
//   flush: val = ((int)(half - cnt*BIAS)) / SCALE, cnt = in-window degree
//   (biased adds stay positive; low-half sum << 2^31 so no carry into high)
// Pipeline: zero, hist, scan, reorder, dinv(+deg+node1), acc1(+MLP), acc2.
// Workspace: 32KB counters | dinv 4N | deg 4N | xs 4N | h2s 4N | perm 4E.

constexpr int W_SHIFT = 10;
constexpr int W = 1024;            // nodes per dst window
constexpr int MAXB = 1024;         // max buckets
constexpr int RB = 512;            // reorder block threads
constexpr int CHUNK = 8192;        // edges per reorder block
constexpr int AB = 512;            // accumulate block threads

constexpr float SCALE1 = 65536.0f;        // 2^16
constexpr float INV1   = 1.0f / 65536.0f;
constexpr unsigned BIAS1 = 1u << 20;
constexpr float SCALE2 = 4096.0f;         // 2^12
constexpr float INV2   = 1.0f / 4096.0f;
constexpr unsigned BIAS2 = 1u << 22;

__device__ __forceinline__ unsigned long long pack2(float a, float b,
                                                    float scale, unsigned bias) {
    unsigned lo = (unsigned)(__float2int_rn(a * scale) + (int)bias);
    unsigned hi = (unsigned)(__float2int_rn(b * scale) + (int)bias);
    return (unsigned long long)lo | ((unsigned long long)hi << 32);
}

__global__ __launch_bounds__(256) void k_zero(unsigned* __restrict__ cnt, int nb) {
    int i = blockIdx.x * 256 + threadIdx.x;
    if (i < nb) cnt[i] = 0u;
}

__global__ __launch_bounds__(256) void k_hist(const int* __restrict__ dst,
                                              unsigned* __restrict__ cnt, int E, int nb) {
    __shared__ unsigned h[MAXB];
    for (int i = threadIdx.x; i < nb; i += 256) h[i] = 0u;
    __syncthreads();
    for (long e = blockIdx.x * 256l + threadIdx.x; e < E; e += (long)gridDim.x * 256)
        atomicAdd(&h[((unsigned)dst[e]) >> W_SHIFT], 1u);
    __syncthreads();
    for (int i = threadIdx.x; i < nb; i += 256) {
        unsigned v = h[i];
        if (v) atomicAdd(&cnt[i], v);
    }
}

__global__ __launch_bounds__(1024) void k_scan(const unsigned* __restrict__ cnt,
                                               unsigned* __restrict__ base,
                                               unsigned* __restrict__ fill, int nb) {
    __shared__ unsigned s[1024];
    int t = threadIdx.x;
    unsigned v = (t < nb) ? cnt[t] : 0u;
    s[t] = v;
    __syncthreads();
    for (int off = 1; off < 1024; off <<= 1) {
        unsigned u = (t >= off) ? s[t - off] : 0u;
        __syncthreads();
        s[t] += u;
        __syncthreads();
    }
    unsigned ex = s[t] - v;
    if (t < nb) { base[t] = ex; fill[t] = ex; }
    if (t == 1023) base[nb] = s[1023];
}

__global__ __launch_bounds__(RB) void k_reorder(const int* __restrict__ src,
                                                const int* __restrict__ dst,
                                                unsigned* __restrict__ fill,
                                                unsigned* __restrict__ perm,
                                                int E, int nb) {
    __shared__ unsigned hist[MAXB];
    __shared__ unsigned sval[CHUNK];
    __shared__ unsigned short sb[CHUNK];
    for (int i = threadIdx.x; i < nb; i += RB) hist[i] = 0u;
    __syncthreads();
    long base0 = (long)blockIdx.x * CHUNK;
    #pragma unroll
    for (int k = 0; k < CHUNK / RB; k++) {
        int li = k * RB + threadIdx.x;
        long e = base0 + li;
        if (e < E) {
            unsigned s = (unsigned)src[e], d = (unsigned)dst[e];
            unsigned b = d >> W_SHIFT, loc = d & (W - 1);
            sval[li] = s | (loc << 20);
            sb[li] = (unsigned short)b;
            atomicAdd(&hist[b], 1u);
        } else {
            sb[li] = 0xFFFFu;
        }
    }
    __syncthreads();
    for (int b = threadIdx.x; b < nb; b += RB) {
        unsigned c = hist[b];
        if (c) hist[b] = atomicAdd(&fill[b], c);  // hist[b] -> running write ptr
    }
    __syncthreads();
    #pragma unroll
    for (int k = 0; k < CHUNK / RB; k++) {
        int li = k * RB + threadIdx.x;
        unsigned b = sb[li];
        if (b != 0xFFFFu) {
            unsigned idx = atomicAdd(&hist[b], 1u);
            perm[idx] = sval[li];
        }
    }
}

// degree count + dinv + deg + xs = half2(x*dinv), fused
__global__ __launch_bounds__(AB) void k_dinv(const unsigned* __restrict__ perm,
                                             const unsigned* __restrict__ base,
                                             const float2* __restrict__ x,
                                             float* __restrict__ dinv,
                                             unsigned* __restrict__ deg,
                                             __half2* __restrict__ xs, int N) {
    __shared__ unsigned c[W];
    for (int i = threadIdx.x; i < W; i += AB) c[i] = 0u;
    __syncthreads();
    int b = blockIdx.x;
    unsigned s = base[b], e = base[b + 1];
    for (unsigned i = s + threadIdx.x; i < e; i += AB)
        atomicAdd(&c[__builtin_nontemporal_load(perm + i) >> 20], 1u);
    __syncthreads();
    int d0 = b << W_SHIFT;
    for (int l = threadIdx.x; l < W; l += AB) {
        int d = d0 + l;
        if (d < N) {
            unsigned cn = c[l];
            float dv = 1.0f / sqrtf((float)(cn + 1u));  // +1 self-loop
            dinv[d] = dv;
            deg[d] = cn;                                // in-window degree (no self)
            float2 xv = x[d];
            xs[d] = __floats2half2_rn(xv.x * dv, xv.y * dv);
        }
    }
}

// layer1 aggregate (1 u64 fixed-point atomic/edge) + full node MLP at flush
__global__ __launch_bounds__(AB) void k_acc1(const unsigned* __restrict__ perm,
                                             const unsigned* __restrict__ base,
                                             const __half2* __restrict__ xs,
                                             const float* __restrict__ dinv,
                                             const unsigned* __restrict__ deg,
                                             const float* __restrict__ W1,
                                             const float* __restrict__ b1,
                                             const float* __restrict__ W2,
                                             __half2* __restrict__ h2s, int N) {
    __shared__ unsigned long long acc[W];
    for (int i = threadIdx.x; i < W; i += AB) acc[i] = 0ull;
    __syncthreads();
    int b = blockIdx.x;
    unsigned s = base[b], e = base[b + 1];
    unsigned i = s + threadIdx.x;
    for (; i + 3u * AB < e; i += 4u * AB) {
        unsigned p0 = __builtin_nontemporal_load(perm + i);
        unsigned p1 = __builtin_nontemporal_load(perm + i + AB);
        unsigned p2 = __builtin_nontemporal_load(perm + i + 2u * AB);
        unsigned p3 = __builtin_nontemporal_load(perm + i + 3u * AB);
        float2 v0 = __half22float2(xs[p0 & 0xFFFFFu]);
        float2 v1 = __half22float2(xs[p1 & 0xFFFFFu]);
        float2 v2 = __half22float2(xs[p2 & 0xFFFFFu]);
        float2 v3 = __half22float2(xs[p3 & 0xFFFFFu]);
        atomicAdd(&acc[p0 >> 20], pack2(v0.x, v0.y, SCALE1, BIAS1));
        atomicAdd(&acc[p1 >> 20], pack2(v1.x, v1.y, SCALE1, BIAS1));
        atomicAdd(&acc[p2 >> 20], pack2(v2.x, v2.y, SCALE1, BIAS1));
        atomicAdd(&acc[p3 >> 20], pack2(v3.x, v3.y, SCALE1, BIAS1));
    }
    for (; i < e; i += AB) {
        unsigned p = __builtin_nontemporal_load(perm + i);
        float2 v = __half22float2(xs[p & 0xFFFFFu]);
        atomicAdd(&acc[p >> 20], pack2(v.x, v.y, SCALE1, BIAS1));
    }
    __syncthreads();
    int d0 = b << W_SHIFT;
    float w10 = W1[0], w11 = W1[1], w12 = W1[2], w13 = W1[3];
    float w14 = W1[4], w15 = W1[5], w16 = W1[6], w17 = W1[7];
    float bb0 = b1[0], bb1 = b1[1], bb2 = b1[2], bb3 = b1[3];
    float u0 = W2[0], u1 = W2[1], u2 = W2[2], u3 = W2[3];
    float u4 = W2[4], u5 = W2[5], u6 = W2[6], u7 = W2[7];
    for (int l = threadIdx.x; l < W; l += AB) {
        int d = d0 + l;
        if (d < N) {
            float dv = dinv[d];
            unsigned cn = deg[d];
            unsigned long long a64 = acc[l];
            unsigned lo = (unsigned)a64, hi = (unsigned)(a64 >> 32);
            float2 self = __half22float2(xs[d]);
            float Sx = (float)(int)(lo - cn * BIAS1) * INV1 + self.x;
            float Sy = (float)(int)(hi - cn * BIAS1) * INV1 + self.y;
            // agg1 = (S @ W1) * dv ; a = relu(agg1 + b1)
            float a0 = fmaxf(fmaf(Sy, w14, Sx * w10) * dv + bb0, 0.0f);
            float a1 = fmaxf(fmaf(Sy, w15, Sx * w11) * dv + bb1, 0.0f);
            float a2 = fmaxf(fmaf(Sy, w16, Sx * w12) * dv + bb2, 0.0f);
            float a3 = fmaxf(fmaf(Sy, w17, Sx * w13) * dv + bb3, 0.0f);
            float hx = (a0 * u0 + a1 * u2 + a2 * u4 + a3 * u6) * dv;
            float hy = (a0 * u1 + a1 * u3 + a2 * u5 + a3 * u7) * dv;
            h2s[d] = __floats2half2_rn(hx, hy);
        }
    }
}

__global__ __launch_bounds__(AB) void k_acc2(const unsigned* __restrict__ perm,
                                             const unsigned* __restrict__ base,
                                             const __half2* __restrict__ h2s,
                                             const float* __restrict__ dinv,
                                             const unsigned* __restrict__ deg,
                                             const float* __restrict__ b2,
                                             float2* __restrict__ out, int N) {
    __shared__ unsigned long long acc[W];
    for (int i = threadIdx.x; i < W; i += AB) acc[i] = 0ull;
    __syncthreads();
    int b = blockIdx.x;
    unsigned s = base[b], e = base[b + 1];
    unsigned i = s + threadIdx.x;
    for (; i + 3u * AB < e; i += 4u * AB) {
        unsigned p0 = __builtin_nontemporal_load(perm + i);
        unsigned p1 = __builtin_nontemporal_load(perm + i + AB);
        unsigned p2 = __builtin_nontemporal_load(perm + i + 2u * AB);
        unsigned p3 = __builtin_nontemporal_load(perm + i + 3u * AB);
        float2 v0 = __half22float2(h2s[p0 & 0xFFFFFu]);
        float2 v1 = __half22float2(h2s[p1 & 0xFFFFFu]);
        float2 v2 = __half22float2(h2s[p2 & 0xFFFFFu]);
        float2 v3 = __half22float2(h2s[p3 & 0xFFFFFu]);
        atomicAdd(&acc[p0 >> 20], pack2(v0.x, v0.y, SCALE2, BIAS2));
        atomicAdd(&acc[p1 >> 20], pack2(v1.x, v1.y, SCALE2, BIAS2));
        atomicAdd(&acc[p2 >> 20], pack2(v2.x, v2.y, SCALE2, BIAS2));
        atomicAdd(&acc[p3 >> 20], pack2(v3.x, v3.y, SCALE2, BIAS2));
    }
    for (; i < e; i += AB) {
        unsigned p = __builtin_nontemporal_load(perm + i);
        float2 v = __half22float2(h2s[p & 0xFFFFFu]);
        atomicAdd(&acc[p >> 20], pack2(v.x, v.y, SCALE2, BIAS2));
    }
    __syncthreads();
    int d0 = b << W_SHIFT;
    float bb0 = b2[0], bb1 = b2[1];
    for (int l = threadIdx.x; l < W; l += AB) {
        int d = d0 + l;
        if (d < N) {
            float dv = dinv[d];
            unsigned cn = deg[d];
            unsigned long long a64 = acc[l];
            unsigned lo = (unsigned)a64, hi = (unsigned)(a64 >> 32);
            float2 v = __half22float2(h2s[d]);  // self-loop message
            float Sx = (float)(int)(lo - cn * BIAS2) * INV2 + v.x;
            float Sy = (float)(int)(hi - cn * BIAS2) * INV2 + v.y;
            out[d] = make_float2(Sx * dv + bb0, Sy * dv + bb1);
        }
    }
}

// ---------------- fallback (R1-style, only if workspace too small) ----------

__global__ __launch_bounds__(256) void f_init_deg(unsigned* deg, int n) {
    int i = blockIdx.x * 256 + threadIdx.x;
    if (i < n) deg[i] = 1u;
}
__global__ __launch_bounds__(256) void f_count_deg(const int* dst, unsigned* deg, int E) {
    int e = blockIdx.x * 256 + threadIdx.x;
    if (e < E) atomicAdd(&deg[dst[e]], 1u);
}
__global__ __launch_bounds__(256) void f_node1(const float2* x, const float* W1,
                                               const unsigned* deg, float* dinv,
                                               float4* h1s, float4* agg1, int n) {
    int i = blockIdx.x * 256 + threadIdx.x;
    if (i >= n) return;
    float dv = 1.0f / sqrtf((float)deg[i]);
    dinv[i] = dv;
    float2 xv = x[i];
    float4 h;
    h.x = fmaf(xv.y, W1[4], xv.x * W1[0]) * dv;
    h.y = fmaf(xv.y, W1[5], xv.x * W1[1]) * dv;
    h.z = fmaf(xv.y, W1[6], xv.x * W1[2]) * dv;
    h.w = fmaf(xv.y, W1[7], xv.x * W1[3]) * dv;
    h1s[i] = h;
    agg1[i] = make_float4(h.x * dv, h.y * dv, h.z * dv, h.w * dv);
}
__global__ __launch_bounds__(256) void f_edge1(const int* src, const int* dst,
                                               const float* dinv, const float4* h1s,
                                               float* agg1, int E) {
    int e = blockIdx.x * 256 + threadIdx.x;
    if (e >= E) return;
    int s = src[e], d = dst[e];
    float w = dinv[d];
    float4 m = h1s[s];
    float* p = agg1 + 4ll * d;
    unsafeAtomicAdd(p + 0, m.x * w);
    unsafeAtomicAdd(p + 1, m.y * w);
    unsafeAtomicAdd(p + 2, m.z * w);
    unsafeAtomicAdd(p + 3, m.w * w);
}
__global__ __launch_bounds__(256) void f_node2(const float4* agg1, const float* b1,
                                               const float* W2, const float* b2,
                                               const float* dinv, float2* h2s,
                                               float2* out, int n) {
    int i = blockIdx.x * 256 + threadIdx.x;
    if (i >= n) return;
    float4 a = agg1[i];
    a.x = fmaxf(a.x + b1[0], 0.0f);
    a.y = fmaxf(a.y + b1[1], 0.0f);
    a.z = fmaxf(a.z + b1[2], 0.0f);
    a.w = fmaxf(a.w + b1[3], 0.0f);
    float dv = dinv[i];
    float2 h;
    h.x = (a.x * W2[0] + a.y * W2[2] + a.z * W2[4] + a.w * W2[6]) * dv;
    h.y = (a.x * W2[1] + a.y * W2[3] + a.z * W2[5] + a.w * W2[7]) * dv;
    h2s[i] = h;
    out[i] = make_float2(b2[0] + h.x * dv, b2[1] + h.y * dv);
}
__global__ __launch_bounds__(256) void f_edge2(const int* src, const int* dst,
                                               const float* dinv, const float2* h2s,
                                               float* out, int E) {
    int e = blockIdx.x * 256 + threadIdx.x;
    if (e >= E) return;
    int s = src[e], d = dst[e];
    float w = dinv[d];
    float2 m = h2s[s];
    float* p = out + 2ll * d;
    unsafeAtomicAdd(p + 0, m.x * w);
    unsafeAtomicAdd(p + 1, m.y * w);
}

extern "C" void kernel_launch(void* const* d_in, const int* in_sizes, int n_in,
                              void* d_out, int out_size, void* d_ws, size_t ws_size,
                              hipStream_t stream) {
    const float* x  = (const float*)d_in[0];
    const int* ei   = (const int*)d_in[1];
    const float* W1 = (const float*)d_in[2];
    const float* b1 = (const float*)d_in[3];
    const float* W2 = (const float*)d_in[4];
    const float* b2 = (const float*)d_in[5];
    float* out = (float*)d_out;

    const int N = in_sizes[0] / 2;
    const int E = in_sizes[1] / 2;
    const int* src = ei;
    const int* dst = ei + E;
    const int NB = (N + W - 1) >> W_SHIFT;

    char* ws = (char*)d_ws;
    const int gN = (N + 255) / 256;
    const int gE = (E + 255) / 256;

    // fast ws: counters 32KB | dinv 4N | deg 4N | xs 4N | h2s 4N | perm 4E
    size_t need = 32768 + (size_t)16 * N + (size_t)4 * E;
    bool fast = (ws_size >= need) && (NB <= MAXB) && (N <= (1 << 20));

    if (fast) {
        unsigned* bucket_cnt  = (unsigned*)(ws);
        unsigned* bucket_base = (unsigned*)(ws + 8192);
        unsigned* bucket_fill = (unsigned*)(ws + 16384);
        float*    dinv = (float*)(ws + 32768);
        unsigned* deg  = (unsigned*)(ws + 32768 + (size_t)4 * N);
        __half2*  xs   = (__half2*)(ws + 32768 + (size_t)8 * N);
        __half2*  h2s  = (__half2*)(ws + 32768 + (size_t)12 * N);
        unsigned* perm = (unsigned*)(ws + 32768 + (size_t)16 * N);

        k_zero<<<(NB + 255) / 256, 256, 0, stream>>>(bucket_cnt, NB);
        k_hist<<<2048, 256, 0, stream>>>(dst, bucket_cnt, E, NB);
        k_scan<<<1, 1024, 0, stream>>>(bucket_cnt, bucket_base, bucket_fill, NB);
        k_reorder<<<(E + CHUNK - 1) / CHUNK, RB, 0, stream>>>(src, dst, bucket_fill, perm, E, NB);
        k_dinv<<<NB, AB, 0, stream>>>(perm, bucket_base, (const float2*)x, dinv, deg, xs, N);
        k_acc1<<<NB, AB, 0, stream>>>(perm, bucket_base, xs, dinv, deg, W1, b1, W2, h2s, N);
        k_acc2<<<NB, AB, 0, stream>>>(perm, bucket_base, h2s, dinv, deg, b2, (float2*)out, N);
    } else {
        unsigned* deg = (unsigned*)(ws);
        float* dinv   = (float*)(ws + (size_t)4 * N);
        float* h1s    = (float*)(ws + (size_t)8 * N);
        float* agg1   = (float*)(ws + (size_t)24 * N);
        float* h2s    = h1s;

        f_init_deg<<<gN, 256, 0, stream>>>(deg, N);
        f_count_deg<<<gE, 256, 0, stream>>>(dst, deg, E);
        f_node1<<<gN, 256, 0, stream>>>((const float2*)x, W1, deg, dinv,
                                        (float4*)h1s, (float4*)agg1, N);
        f_edge1<<<gE, 256, 0, stream>>>(src, dst, dinv, (const float4*)h1s, agg1, E);
        f_node2<<<gN, 256, 0, stream>>>((const float4*)agg1, b1, W2, b2, dinv,
                                        (float2*)h2s, (float2*)out, N);
        f_edge2<<<gE, 256, 0, stream>>>(src, dst, dinv, (const float2*)h2s, out, E);
    }
}

// Round 6
// 479.768 us; speedup vs baseline: 11.3686x; 1.2062x over previous
//
#include <hip/hip_runtime.h>
#include <hip/hip_fp16.h>

// GCN 2-layer forward, MI355X. R6: slab-allocated multisplit reorder.
// vs R5 (k_reorder 152us top kernel: 280MB WRITE from 16M scattered 4B
// writes ~64 transactions/wave; plus hist+scan feeders ~45us):
//  - fixed-capacity slab per window (C~21K >= mean 16.4K + 35sigma), fill[b]
//    seeded to b*C  =>  k_hist / k_scan deleted.
//  - reorder = LDS multisplit: local hist -> block scan -> LDS-sorted staging
//    -> sequential sweep writing perm[gdelta[b]+t]; piecewise-contiguous
//    targets coalesce (~8 edges/run) instead of 64x 4B scatter.
// acc kernels keep R5's 1x u64 fixed-point LDS atomic/edge (proven governor).
// Pipeline: zero(fill=b*C), reorder, dinv(+deg+xs), acc1(+full MLP), acc2.
// Workspace: 32KB | dinv 4N | deg 4N | xs 4N | h2s 4N | perm NB*C*4 (~84MB).

constexpr int W_SHIFT = 10;
constexpr int W = 1024;            // nodes per dst window
constexpr int MAXB = 1024;         // max buckets (scan width)
constexpr int RB = 1024;           // reorder block threads
constexpr int CHUNK = 8192;        // edges per reorder block
constexpr int RIT = CHUNK / RB;    // 8 edges/thread
constexpr int AB = 512;            // accumulate block threads

constexpr float SCALE1 = 65536.0f;        // 2^16
constexpr float INV1   = 1.0f / 65536.0f;
constexpr unsigned BIAS1 = 1u << 20;
constexpr float SCALE2 = 4096.0f;         // 2^12
constexpr float INV2   = 1.0f / 4096.0f;
constexpr unsigned BIAS2 = 1u << 22;

__device__ __forceinline__ unsigned long long pack2(float a, float b,
                                                    float scale, unsigned bias) {
    unsigned lo = (unsigned)(__float2int_rn(a * scale) + (int)bias);
    unsigned hi = (unsigned)(__float2int_rn(b * scale) + (int)bias);
    return (unsigned long long)lo | ((unsigned long long)hi << 32);
}

__global__ __launch_bounds__(256) void k_zero_fill(unsigned* __restrict__ fill,
                                                   int nb, unsigned C) {
    int i = blockIdx.x * 256 + threadIdx.x;
    if (i < nb) fill[i] = (unsigned)i * C;
}

// LDS multisplit: bin CHUNK edges into dst windows with coalesced output.
__global__ __launch_bounds__(RB) void k_reorder(const int* __restrict__ src,
                                                const int* __restrict__ dst,
                                                unsigned* __restrict__ fill,
                                                unsigned* __restrict__ perm, int E) {
    __shared__ unsigned hist[MAXB];     // counts -> running local ptr
    __shared__ unsigned lbase[MAXB];    // scan scratch -> exclusive local base
    __shared__ unsigned gdelta[MAXB];   // globalBase - localBase
    __shared__ unsigned sorted[CHUNK];  // vals in locally-sorted order
    __shared__ unsigned short sbb[CHUNK]; // bucket of sorted[t]
    int tid = threadIdx.x;
    hist[tid] = 0u;
    __syncthreads();
    long base0 = (long)blockIdx.x * CHUNK;
    int total = (int)min((long)CHUNK, (long)E - base0);
    #pragma unroll
    for (int k = 0; k < RIT; k++) {
        int li = k * RB + tid;
        if (li < total)
            atomicAdd(&hist[((unsigned)dst[base0 + li]) >> W_SHIFT], 1u);
    }
    __syncthreads();
    // inclusive Hillis-Steele scan over 1024 buckets
    unsigned v = hist[tid];
    lbase[tid] = v;
    __syncthreads();
    for (int off = 1; off < MAXB; off <<= 1) {
        unsigned u = (tid >= off) ? lbase[tid - off] : 0u;
        __syncthreads();
        lbase[tid] += u;
        __syncthreads();
    }
    unsigned excl = lbase[tid] - v;
    unsigned gd = 0u;
    if (v) {
        unsigned g = atomicAdd(&fill[tid], v);  // reserve global slab space
        gd = g - excl;
    }
    __syncthreads();
    gdelta[tid] = gd;
    hist[tid] = excl;   // running local write ptr
    __syncthreads();
    #pragma unroll
    for (int k = 0; k < RIT; k++) {
        int li = k * RB + tid;
        if (li < total) {
            unsigned d = (unsigned)dst[base0 + li];   // L2-hot re-read
            unsigned s = (unsigned)src[base0 + li];
            unsigned b = d >> W_SHIFT;
            unsigned lpos = atomicAdd(&hist[b], 1u);
            sorted[lpos] = s | ((d & (W - 1)) << 20);
            sbb[lpos] = (unsigned short)b;
        }
    }
    __syncthreads();
    #pragma unroll
    for (int k = 0; k < RIT; k++) {
        int t = k * RB + tid;
        if (t < total) {
            unsigned b = sbb[t];
            perm[gdelta[b] + t] = sorted[t];   // piecewise-contiguous targets
        }
    }
}

// degree count + dinv + deg + xs = half2(x*dinv), fused
__global__ __launch_bounds__(AB) void k_dinv(const unsigned* __restrict__ perm,
                                             const unsigned* __restrict__ fill,
                                             const float2* __restrict__ x,
                                             float* __restrict__ dinv,
                                             unsigned* __restrict__ deg,
                                             __half2* __restrict__ xs,
                                             int N, unsigned C) {
    __shared__ unsigned c[W];
    for (int i = threadIdx.x; i < W; i += AB) c[i] = 0u;
    __syncthreads();
    int b = blockIdx.x;
    unsigned s = (unsigned)b * C, e = fill[b];
    for (unsigned i = s + threadIdx.x; i < e; i += AB)
        atomicAdd(&c[__builtin_nontemporal_load(perm + i) >> 20], 1u);
    __syncthreads();
    int d0 = b << W_SHIFT;
    for (int l = threadIdx.x; l < W; l += AB) {
        int d = d0 + l;
        if (d < N) {
            unsigned cn = c[l];
            float dv = 1.0f / sqrtf((float)(cn + 1u));  // +1 self-loop
            dinv[d] = dv;
            deg[d] = cn;
            float2 xv = x[d];
            xs[d] = __floats2half2_rn(xv.x * dv, xv.y * dv);
        }
    }
}

// layer1 aggregate (1 u64 fixed-point atomic/edge) + full node MLP at flush
__global__ __launch_bounds__(AB) void k_acc1(const unsigned* __restrict__ perm,
                                             const unsigned* __restrict__ fill,
                                             const __half2* __restrict__ xs,
                                             const float* __restrict__ dinv,
                                             const unsigned* __restrict__ deg,
                                             const float* __restrict__ W1,
                                             const float* __restrict__ b1,
                                             const float* __restrict__ W2,
                                             __half2* __restrict__ h2s,
                                             int N, unsigned C) {
    __shared__ unsigned long long acc[W];
    for (int i = threadIdx.x; i < W; i += AB) acc[i] = 0ull;
    __syncthreads();
    int b = blockIdx.x;
    unsigned s = (unsigned)b * C, e = fill[b];
    unsigned i = s + threadIdx.x;
    for (; i + 3u * AB < e; i += 4u * AB) {
        unsigned p0 = __builtin_nontemporal_load(perm + i);
        unsigned p1 = __builtin_nontemporal_load(perm + i + AB);
        unsigned p2 = __builtin_nontemporal_load(perm + i + 2u * AB);
        unsigned p3 = __builtin_nontemporal_load(perm + i + 3u * AB);
        float2 v0 = __half22float2(xs[p0 & 0xFFFFFu]);
        float2 v1 = __half22float2(xs[p1 & 0xFFFFFu]);
        float2 v2 = __half22float2(xs[p2 & 0xFFFFFu]);
        float2 v3 = __half22float2(xs[p3 & 0xFFFFFu]);
        atomicAdd(&acc[p0 >> 20], pack2(v0.x, v0.y, SCALE1, BIAS1));
        atomicAdd(&acc[p1 >> 20], pack2(v1.x, v1.y, SCALE1, BIAS1));
        atomicAdd(&acc[p2 >> 20], pack2(v2.x, v2.y, SCALE1, BIAS1));
        atomicAdd(&acc[p3 >> 20], pack2(v3.x, v3.y, SCALE1, BIAS1));
    }
    for (; i < e; i += AB) {
        unsigned p = __builtin_nontemporal_load(perm + i);
        float2 v = __half22float2(xs[p & 0xFFFFFu]);
        atomicAdd(&acc[p >> 20], pack2(v.x, v.y, SCALE1, BIAS1));
    }
    __syncthreads();
    int d0 = b << W_SHIFT;
    float w10 = W1[0], w11 = W1[1], w12 = W1[2], w13 = W1[3];
    float w14 = W1[4], w15 = W1[5], w16 = W1[6], w17 = W1[7];
    float bb0 = b1[0], bb1 = b1[1], bb2 = b1[2], bb3 = b1[3];
    float u0 = W2[0], u1 = W2[1], u2 = W2[2], u3 = W2[3];
    float u4 = W2[4], u5 = W2[5], u6 = W2[6], u7 = W2[7];
    for (int l = threadIdx.x; l < W; l += AB) {
        int d = d0 + l;
        if (d < N) {
            float dv = dinv[d];
            unsigned cn = deg[d];
            unsigned long long a64 = acc[l];
            unsigned lo = (unsigned)a64, hi = (unsigned)(a64 >> 32);
            float2 self = __half22float2(xs[d]);
            float Sx = (float)(int)(lo - cn * BIAS1) * INV1 + self.x;
            float Sy = (float)(int)(hi - cn * BIAS1) * INV1 + self.y;
            float a0 = fmaxf(fmaf(Sy, w14, Sx * w10) * dv + bb0, 0.0f);
            float a1 = fmaxf(fmaf(Sy, w15, Sx * w11) * dv + bb1, 0.0f);
            float a2 = fmaxf(fmaf(Sy, w16, Sx * w12) * dv + bb2, 0.0f);
            float a3 = fmaxf(fmaf(Sy, w17, Sx * w13) * dv + bb3, 0.0f);
            float hx = (a0 * u0 + a1 * u2 + a2 * u4 + a3 * u6) * dv;
            float hy = (a0 * u1 + a1 * u3 + a2 * u5 + a3 * u7) * dv;
            h2s[d] = __floats2half2_rn(hx, hy);
        }
    }
}

__global__ __launch_bounds__(AB) void k_acc2(const unsigned* __restrict__ perm,
                                             const unsigned* __restrict__ fill,
                                             const __half2* __restrict__ h2s,
                                             const float* __restrict__ dinv,
                                             const unsigned* __restrict__ deg,
                                             const float* __restrict__ b2,
                                             float2* __restrict__ out,
                                             int N, unsigned C) {
    __shared__ unsigned long long acc[W];
    for (int i = threadIdx.x; i < W; i += AB) acc[i] = 0ull;
    __syncthreads();
    int b = blockIdx.x;
    unsigned s = (unsigned)b * C, e = fill[b];
    unsigned i = s + threadIdx.x;
    for (; i + 3u * AB < e; i += 4u * AB) {
        unsigned p0 = __builtin_nontemporal_load(perm + i);
        unsigned p1 = __builtin_nontemporal_load(perm + i + AB);
        unsigned p2 = __builtin_nontemporal_load(perm + i + 2u * AB);
        unsigned p3 = __builtin_nontemporal_load(perm + i + 3u * AB);
        float2 v0 = __half22float2(h2s[p0 & 0xFFFFFu]);
        float2 v1 = __half22float2(h2s[p1 & 0xFFFFFu]);
        float2 v2 = __half22float2(h2s[p2 & 0xFFFFFu]);
        float2 v3 = __half22float2(h2s[p3 & 0xFFFFFu]);
        atomicAdd(&acc[p0 >> 20], pack2(v0.x, v0.y, SCALE2, BIAS2));
        atomicAdd(&acc[p1 >> 20], pack2(v1.x, v1.y, SCALE2, BIAS2));
        atomicAdd(&acc[p2 >> 20], pack2(v2.x, v2.y, SCALE2, BIAS2));
        atomicAdd(&acc[p3 >> 20], pack2(v3.x, v3.y, SCALE2, BIAS2));
    }
    for (; i < e; i += AB) {
        unsigned p = __builtin_nontemporal_load(perm + i);
        float2 v = __half22float2(h2s[p & 0xFFFFFu]);
        atomicAdd(&acc[p >> 20], pack2(v.x, v.y, SCALE2, BIAS2));
    }
    __syncthreads();
    int d0 = b << W_SHIFT;
    float bb0 = b2[0], bb1 = b2[1];
    for (int l = threadIdx.x; l < W; l += AB) {
        int d = d0 + l;
        if (d < N) {
            float dv = dinv[d];
            unsigned cn = deg[d];
            unsigned long long a64 = acc[l];
            unsigned lo = (unsigned)a64, hi = (unsigned)(a64 >> 32);
            float2 v = __half22float2(h2s[d]);
            float Sx = (float)(int)(lo - cn * BIAS2) * INV2 + v.x;
            float Sy = (float)(int)(hi - cn * BIAS2) * INV2 + v.y;
            out[d] = make_float2(Sx * dv + bb0, Sy * dv + bb1);
        }
    }
}

// ---------------- fallback (R1-style, only if workspace too small) ----------

__global__ __launch_bounds__(256) void f_init_deg(unsigned* deg, int n) {
    int i = blockIdx.x * 256 + threadIdx.x;
    if (i < n) deg[i] = 1u;
}
__global__ __launch_bounds__(256) void f_count_deg(const int* dst, unsigned* deg, int E) {
    int e = blockIdx.x * 256 + threadIdx.x;
    if (e < E) atomicAdd(&deg[dst[e]], 1u);
}
__global__ __launch_bounds__(256) void f_node1(const float2* x, const float* W1,
                                               const unsigned* deg, float* dinv,
                                               float4* h1s, float4* agg1, int n) {
    int i = blockIdx.x * 256 + threadIdx.x;
    if (i >= n) return;
    float dv = 1.0f / sqrtf((float)deg[i]);
    dinv[i] = dv;
    float2 xv = x[i];
    float4 h;
    h.x = fmaf(xv.y, W1[4], xv.x * W1[0]) * dv;
    h.y = fmaf(xv.y, W1[5], xv.x * W1[1]) * dv;
    h.z = fmaf(xv.y, W1[6], xv.x * W1[2]) * dv;
    h.w = fmaf(xv.y, W1[7], xv.x * W1[3]) * dv;
    h1s[i] = h;
    agg1[i] = make_float4(h.x * dv, h.y * dv, h.z * dv, h.w * dv);
}
__global__ __launch_bounds__(256) void f_edge1(const int* src, const int* dst,
                                               const float* dinv, const float4* h1s,
                                               float* agg1, int E) {
    int e = blockIdx.x * 256 + threadIdx.x;
    if (e >= E) return;
    int s = src[e], d = dst[e];
    float w = dinv[d];
    float4 m = h1s[s];
    float* p = agg1 + 4ll * d;
    unsafeAtomicAdd(p + 0, m.x * w);
    unsafeAtomicAdd(p + 1, m.y * w);
    unsafeAtomicAdd(p + 2, m.z * w);
    unsafeAtomicAdd(p + 3, m.w * w);
}
__global__ __launch_bounds__(256) void f_node2(const float4* agg1, const float* b1,
                                               const float* W2, const float* b2,
                                               const float* dinv, float2* h2s,
                                               float2* out, int n) {
    int i = blockIdx.x * 256 + threadIdx.x;
    if (i >= n) return;
    float4 a = agg1[i];
    a.x = fmaxf(a.x + b1[0], 0.0f);
    a.y = fmaxf(a.y + b1[1], 0.0f);
    a.z = fmaxf(a.z + b1[2], 0.0f);
    a.w = fmaxf(a.w + b1[3], 0.0f);
    float dv = dinv[i];
    float2 h;
    h.x = (a.x * W2[0] + a.y * W2[2] + a.z * W2[4] + a.w * W2[6]) * dv;
    h.y = (a.x * W2[1] + a.y * W2[3] + a.z * W2[5] + a.w * W2[7]) * dv;
    h2s[i] = h;
    out[i] = make_float2(b2[0] + h.x * dv, b2[1] + h.y * dv);
}
__global__ __launch_bounds__(256) void f_edge2(const int* src, const int* dst,
                                               const float* dinv, const float2* h2s,
                                               float* out, int E) {
    int e = blockIdx.x * 256 + threadIdx.x;
    if (e >= E) return;
    int s = src[e], d = dst[e];
    float w = dinv[d];
    float2 m = h2s[s];
    float* p = out + 2ll * d;
    unsafeAtomicAdd(p + 0, m.x * w);
    unsafeAtomicAdd(p + 1, m.y * w);
}

extern "C" void kernel_launch(void* const* d_in, const int* in_sizes, int n_in,
                              void* d_out, int out_size, void* d_ws, size_t ws_size,
                              hipStream_t stream) {
    const float* x  = (const float*)d_in[0];
    const int* ei   = (const int*)d_in[1];
    const float* W1 = (const float*)d_in[2];
    const float* b1 = (const float*)d_in[3];
    const float* W2 = (const float*)d_in[4];
    const float* b2 = (const float*)d_in[5];
    float* out = (float*)d_out;

    const int N = in_sizes[0] / 2;
    const int E = in_sizes[1] / 2;
    const int* src = ei;
    const int* dst = ei + E;
    const int NB = (N + W - 1) >> W_SHIFT;

    char* ws = (char*)d_ws;
    const int gN = (N + 255) / 256;
    const int gE = (E + 255) / 256;

    // slab capacity: mean fill E/NB (sigma ~ sqrt(E/NB) ~ 128), need >= +2048
    size_t fixed = 32768 + (size_t)16 * N;   // counters | dinv | deg | xs | h2s
    long avail = (long)ws_size - (long)fixed;
    long Cmax = (avail > 0) ? avail / (4L * NB) : 0;
    long Cmin = (long)(E / (NB > 0 ? NB : 1)) + 2048;
    unsigned C = (unsigned)((Cmax > Cmin + 6144) ? (Cmin + 6144) : Cmax);
    bool fast = (Cmax >= Cmin) && (NB <= MAXB) && (N <= (1 << 20));

    if (fast) {
        unsigned* fill = (unsigned*)(ws);                          // NB entries
        float*    dinv = (float*)(ws + 32768);
        unsigned* deg  = (unsigned*)(ws + 32768 + (size_t)4 * N);
        __half2*  xs   = (__half2*)(ws + 32768 + (size_t)8 * N);
        __half2*  h2s  = (__half2*)(ws + 32768 + (size_t)12 * N);
        unsigned* perm = (unsigned*)(ws + fixed);

        k_zero_fill<<<(NB + 255) / 256, 256, 0, stream>>>(fill, NB, C);
        k_reorder<<<(E + CHUNK - 1) / CHUNK, RB, 0, stream>>>(src, dst, fill, perm, E);
        k_dinv<<<NB, AB, 0, stream>>>(perm, fill, (const float2*)x, dinv, deg, xs, N, C);
        k_acc1<<<NB, AB, 0, stream>>>(perm, fill, xs, dinv, deg, W1, b1, W2, h2s, N, C);
        k_acc2<<<NB, AB, 0, stream>>>(perm, fill, h2s, dinv, deg, b2, (float2*)out, N, C);
    } else {
        unsigned* deg = (unsigned*)(ws);
        float* dinv   = (float*)(ws + (size_t)4 * N);
        float* h1s    = (float*)(ws + (size_t)8 * N);
        float* agg1   = (float*)(ws + (size_t)24 * N);
        float* h2s    = h1s;

        f_init_deg<<<gN, 256, 0, stream>>>(deg, N);
        f_count_deg<<<gE, 256, 0, stream>>>(dst, deg, E);
        f_node1<<<gN, 256, 0, stream>>>((const float2*)x, W1, deg, dinv,
                                        (float4*)h1s, (float4*)agg1, N);
        f_edge1<<<gE, 256, 0, stream>>>(src, dst, dinv, (const float4*)h1s, agg1, E);
        f_node2<<<gN, 256, 0, stream>>>((const float4*)agg1, b1, W2, b2, dinv,
                                        (float2*)h2s, (float2*)out, N);
        f_edge2<<<gE, 256, 0, stream>>>(src, dst, dinv, (const float2*)h2s, out, E);
    }
}

// Round 7
// 449.039 us; speedup vs baseline: 12.1466x; 1.0684x over previous
//
#include <hip/hip_runtime.h>
#include <hip/hip_fp16.h>

// GCN 2-layer forward, MI355X. R7: W=2048 windows + vectorized streams.
// vs R6 (480us: reorder 115, dinv+acc1+acc2 ~350 -> per-edge instr bound):
//  - W 1024->2048 (NB=489, MAXB=512): reorder runs 8->16 edges (=64B line)
//    => write amp ~1.8->~1.3; block scan half width. val = src(20b)|loc(11b).
//  - perm read as ext-vector uint4 in dinv/acc1/acc2 (slab base %4==0):
//    load instructions /4 on all three per-edge passes.
//  - reorder reads dst/src as int4 (2 vector loads per 8 edges/thread).
// acc kernels keep 1x u64 fixed-point LDS atomic/edge (R5's proven governor).
// Pipeline: zero(fill=b*C), reorder, dinv(+deg+xs), acc1(+full MLP), acc2.

constexpr int W_SHIFT = 11;
constexpr int W = 2048;            // nodes per dst window
constexpr int MAXB = 512;          // max buckets
constexpr int RB = 1024;           // reorder block threads
constexpr int CHUNK = 8192;        // edges per reorder block
constexpr int AB = 512;            // accumulate block threads

constexpr float SCALE1 = 65536.0f;        // 2^16
constexpr float INV1   = 1.0f / 65536.0f;
constexpr unsigned BIAS1 = 1u << 20;
constexpr float SCALE2 = 4096.0f;         // 2^12
constexpr float INV2   = 1.0f / 4096.0f;
constexpr unsigned BIAS2 = 1u << 22;

typedef unsigned uv4 __attribute__((ext_vector_type(4)));
typedef int      iv4 __attribute__((ext_vector_type(4)));

__device__ __forceinline__ unsigned long long pack2(float a, float b,
                                                    float scale, unsigned bias) {
    unsigned lo = (unsigned)(__float2int_rn(a * scale) + (int)bias);
    unsigned hi = (unsigned)(__float2int_rn(b * scale) + (int)bias);
    return (unsigned long long)lo | ((unsigned long long)hi << 32);
}

__global__ __launch_bounds__(256) void k_zero_fill(unsigned* __restrict__ fill,
                                                   int nb, unsigned C) {
    int i = blockIdx.x * 256 + threadIdx.x;
    if (i < nb) fill[i] = (unsigned)i * C;
}

// LDS multisplit: bin CHUNK edges into dst windows with coalesced output.
__global__ __launch_bounds__(RB) void k_reorder(const int* __restrict__ src,
                                                const int* __restrict__ dst,
                                                unsigned* __restrict__ fill,
                                                unsigned* __restrict__ perm, int E) {
    __shared__ unsigned hist[MAXB];       // counts -> running local ptr
    __shared__ unsigned lbase[MAXB];      // scan scratch -> inclusive scan
    __shared__ unsigned gdelta[MAXB];     // globalBase - localBase
    __shared__ unsigned sorted[CHUNK];    // vals in locally-sorted order
    __shared__ unsigned short sbb[CHUNK]; // bucket of sorted[t]
    int tid = threadIdx.x;
    if (tid < MAXB) hist[tid] = 0u;
    __syncthreads();
    long base0 = (long)blockIdx.x * CHUNK;
    int total = (int)min((long)CHUNK, (long)E - base0);
    bool full = (total == CHUNK);

    if (full) {
        const iv4* dv4 = (const iv4*)(dst + base0);
        #pragma unroll
        for (int k = 0; k < 2; k++) {
            iv4 q = dv4[k * RB + tid];
            atomicAdd(&hist[((unsigned)q.x) >> W_SHIFT], 1u);
            atomicAdd(&hist[((unsigned)q.y) >> W_SHIFT], 1u);
            atomicAdd(&hist[((unsigned)q.z) >> W_SHIFT], 1u);
            atomicAdd(&hist[((unsigned)q.w) >> W_SHIFT], 1u);
        }
    } else {
        for (int li = tid; li < total; li += RB)
            atomicAdd(&hist[((unsigned)dst[base0 + li]) >> W_SHIFT], 1u);
    }
    __syncthreads();
    // inclusive Hillis-Steele scan over MAXB buckets (threads < MAXB)
    unsigned v = (tid < MAXB) ? hist[tid] : 0u;
    if (tid < MAXB) lbase[tid] = v;
    __syncthreads();
    for (int off = 1; off < MAXB; off <<= 1) {
        unsigned u = (tid >= off && tid < MAXB) ? lbase[tid - off] : 0u;
        __syncthreads();
        if (tid < MAXB) lbase[tid] += u;
        __syncthreads();
    }
    if (tid < MAXB) {
        unsigned excl = lbase[tid] - v;
        unsigned gd = 0u;
        if (v) gd = atomicAdd(&fill[tid], v) - excl;  // reserve slab space
        gdelta[tid] = gd;
        hist[tid] = excl;   // running local write ptr
    }
    __syncthreads();
    if (full) {
        const iv4* dv4 = (const iv4*)(dst + base0);
        const iv4* sv4 = (const iv4*)(src + base0);
        #pragma unroll
        for (int k = 0; k < 2; k++) {
            iv4 dq = dv4[k * RB + tid];
            iv4 sq = sv4[k * RB + tid];
            unsigned d, b, lpos;
            d = (unsigned)dq.x; b = d >> W_SHIFT; lpos = atomicAdd(&hist[b], 1u);
            sorted[lpos] = (unsigned)sq.x | ((d & (W - 1)) << 20); sbb[lpos] = (unsigned short)b;
            d = (unsigned)dq.y; b = d >> W_SHIFT; lpos = atomicAdd(&hist[b], 1u);
            sorted[lpos] = (unsigned)sq.y | ((d & (W - 1)) << 20); sbb[lpos] = (unsigned short)b;
            d = (unsigned)dq.z; b = d >> W_SHIFT; lpos = atomicAdd(&hist[b], 1u);
            sorted[lpos] = (unsigned)sq.z | ((d & (W - 1)) << 20); sbb[lpos] = (unsigned short)b;
            d = (unsigned)dq.w; b = d >> W_SHIFT; lpos = atomicAdd(&hist[b], 1u);
            sorted[lpos] = (unsigned)sq.w | ((d & (W - 1)) << 20); sbb[lpos] = (unsigned short)b;
        }
    } else {
        for (int li = tid; li < total; li += RB) {
            unsigned d = (unsigned)dst[base0 + li];
            unsigned s = (unsigned)src[base0 + li];
            unsigned b = d >> W_SHIFT;
            unsigned lpos = atomicAdd(&hist[b], 1u);
            sorted[lpos] = s | ((d & (W - 1)) << 20);
            sbb[lpos] = (unsigned short)b;
        }
    }
    __syncthreads();
    if (full) {
        #pragma unroll
        for (int k = 0; k < CHUNK / RB; k++) {
            int t = k * RB + tid;
            unsigned b = sbb[t];
            perm[gdelta[b] + t] = sorted[t];   // piecewise-contiguous targets
        }
    } else {
        for (int t = tid; t < total; t += RB) {
            unsigned b = sbb[t];
            perm[gdelta[b] + t] = sorted[t];
        }
    }
}

// degree count + dinv + deg + xs = half2(x*dinv), fused
__global__ __launch_bounds__(AB) void k_dinv(const unsigned* __restrict__ perm,
                                             const unsigned* __restrict__ fill,
                                             const float2* __restrict__ x,
                                             float* __restrict__ dinv,
                                             unsigned* __restrict__ deg,
                                             __half2* __restrict__ xs,
                                             int N, unsigned C) {
    __shared__ unsigned c[W];
    for (int i = threadIdx.x; i < W; i += AB) c[i] = 0u;
    __syncthreads();
    int b = blockIdx.x;
    unsigned s = (unsigned)b * C, e = fill[b];
    unsigned m = e - s, nv = m >> 2;
    const uv4* p4 = (const uv4*)(perm + s);
    for (unsigned j = threadIdx.x; j < nv; j += AB) {
        uv4 q = __builtin_nontemporal_load(p4 + j);
        atomicAdd(&c[q.x >> 20], 1u);
        atomicAdd(&c[q.y >> 20], 1u);
        atomicAdd(&c[q.z >> 20], 1u);
        atomicAdd(&c[q.w >> 20], 1u);
    }
    unsigned t = s + (nv << 2) + threadIdx.x;
    if (t < e) atomicAdd(&c[perm[t] >> 20], 1u);
    __syncthreads();
    int d0 = b << W_SHIFT;
    for (int l = threadIdx.x; l < W; l += AB) {
        int d = d0 + l;
        if (d < N) {
            unsigned cn = c[l];
            float dv = 1.0f / sqrtf((float)(cn + 1u));  // +1 self-loop
            dinv[d] = dv;
            deg[d] = cn;
            float2 xv = x[d];
            xs[d] = __floats2half2_rn(xv.x * dv, xv.y * dv);
        }
    }
}

// layer1 aggregate (1 u64 fixed-point atomic/edge) + full node MLP at flush
__global__ __launch_bounds__(AB) void k_acc1(const unsigned* __restrict__ perm,
                                             const unsigned* __restrict__ fill,
                                             const __half2* __restrict__ xs,
                                             const float* __restrict__ dinv,
                                             const unsigned* __restrict__ deg,
                                             const float* __restrict__ W1,
                                             const float* __restrict__ b1,
                                             const float* __restrict__ W2,
                                             __half2* __restrict__ h2s,
                                             int N, unsigned C) {
    __shared__ unsigned long long acc[W];
    for (int i = threadIdx.x; i < W; i += AB) acc[i] = 0ull;
    __syncthreads();
    int b = blockIdx.x;
    unsigned s = (unsigned)b * C, e = fill[b];
    unsigned m = e - s, nv = m >> 2;
    const uv4* p4 = (const uv4*)(perm + s);
    for (unsigned j = threadIdx.x; j < nv; j += AB) {
        uv4 q = __builtin_nontemporal_load(p4 + j);
        float2 v0 = __half22float2(xs[q.x & 0xFFFFFu]);
        float2 v1 = __half22float2(xs[q.y & 0xFFFFFu]);
        float2 v2 = __half22float2(xs[q.z & 0xFFFFFu]);
        float2 v3 = __half22float2(xs[q.w & 0xFFFFFu]);
        atomicAdd(&acc[q.x >> 20], pack2(v0.x, v0.y, SCALE1, BIAS1));
        atomicAdd(&acc[q.y >> 20], pack2(v1.x, v1.y, SCALE1, BIAS1));
        atomicAdd(&acc[q.z >> 20], pack2(v2.x, v2.y, SCALE1, BIAS1));
        atomicAdd(&acc[q.w >> 20], pack2(v3.x, v3.y, SCALE1, BIAS1));
    }
    unsigned t = s + (nv << 2) + threadIdx.x;
    if (t < e) {
        unsigned p = perm[t];
        float2 v = __half22float2(xs[p & 0xFFFFFu]);
        atomicAdd(&acc[p >> 20], pack2(v.x, v.y, SCALE1, BIAS1));
    }
    __syncthreads();
    int d0 = b << W_SHIFT;
    float w10 = W1[0], w11 = W1[1], w12 = W1[2], w13 = W1[3];
    float w14 = W1[4], w15 = W1[5], w16 = W1[6], w17 = W1[7];
    float bb0 = b1[0], bb1 = b1[1], bb2 = b1[2], bb3 = b1[3];
    float u0 = W2[0], u1 = W2[1], u2 = W2[2], u3 = W2[3];
    float u4 = W2[4], u5 = W2[5], u6 = W2[6], u7 = W2[7];
    for (int l = threadIdx.x; l < W; l += AB) {
        int d = d0 + l;
        if (d < N) {
            float dv = dinv[d];
            unsigned cn = deg[d];
            unsigned long long a64 = acc[l];
            unsigned lo = (unsigned)a64, hi = (unsigned)(a64 >> 32);
            float2 self = __half22float2(xs[d]);
            float Sx = (float)(int)(lo - cn * BIAS1) * INV1 + self.x;
            float Sy = (float)(int)(hi - cn * BIAS1) * INV1 + self.y;
            float a0 = fmaxf(fmaf(Sy, w14, Sx * w10) * dv + bb0, 0.0f);
            float a1 = fmaxf(fmaf(Sy, w15, Sx * w11) * dv + bb1, 0.0f);
            float a2 = fmaxf(fmaf(Sy, w16, Sx * w12) * dv + bb2, 0.0f);
            float a3 = fmaxf(fmaf(Sy, w17, Sx * w13) * dv + bb3, 0.0f);
            float hx = (a0 * u0 + a1 * u2 + a2 * u4 + a3 * u6) * dv;
            float hy = (a0 * u1 + a1 * u3 + a2 * u5 + a3 * u7) * dv;
            h2s[d] = __floats2half2_rn(hx, hy);
        }
    }
}

__global__ __launch_bounds__(AB) void k_acc2(const unsigned* __restrict__ perm,
                                             const unsigned* __restrict__ fill,
                                             const __half2* __restrict__ h2s,
                                             const float* __restrict__ dinv,
                                             const unsigned* __restrict__ deg,
                                             const float* __restrict__ b2,
                                             float2* __restrict__ out,
                                             int N, unsigned C) {
    __shared__ unsigned long long acc[W];
    for (int i = threadIdx.x; i < W; i += AB) acc[i] = 0ull;
    __syncthreads();
    int b = blockIdx.x;
    unsigned s = (unsigned)b * C, e = fill[b];
    unsigned m = e - s, nv = m >> 2;
    const uv4* p4 = (const uv4*)(perm + s);
    for (unsigned j = threadIdx.x; j < nv; j += AB) {
        uv4 q = __builtin_nontemporal_load(p4 + j);
        float2 v0 = __half22float2(h2s[q.x & 0xFFFFFu]);
        float2 v1 = __half22float2(h2s[q.y & 0xFFFFFu]);
        float2 v2 = __half22float2(h2s[q.z & 0xFFFFFu]);
        float2 v3 = __half22float2(h2s[q.w & 0xFFFFFu]);
        atomicAdd(&acc[q.x >> 20], pack2(v0.x, v0.y, SCALE2, BIAS2));
        atomicAdd(&acc[q.y >> 20], pack2(v1.x, v1.y, SCALE2, BIAS2));
        atomicAdd(&acc[q.z >> 20], pack2(v2.x, v2.y, SCALE2, BIAS2));
        atomicAdd(&acc[q.w >> 20], pack2(v3.x, v3.y, SCALE2, BIAS2));
    }
    unsigned t = s + (nv << 2) + threadIdx.x;
    if (t < e) {
        unsigned p = perm[t];
        float2 v = __half22float2(h2s[p & 0xFFFFFu]);
        atomicAdd(&acc[p >> 20], pack2(v.x, v.y, SCALE2, BIAS2));
    }
    __syncthreads();
    int d0 = b << W_SHIFT;
    float bb0 = b2[0], bb1 = b2[1];
    for (int l = threadIdx.x; l < W; l += AB) {
        int d = d0 + l;
        if (d < N) {
            float dv = dinv[d];
            unsigned cn = deg[d];
            unsigned long long a64 = acc[l];
            unsigned lo = (unsigned)a64, hi = (unsigned)(a64 >> 32);
            float2 v = __half22float2(h2s[d]);
            float Sx = (float)(int)(lo - cn * BIAS2) * INV2 + v.x;
            float Sy = (float)(int)(hi - cn * BIAS2) * INV2 + v.y;
            out[d] = make_float2(Sx * dv + bb0, Sy * dv + bb1);
        }
    }
}

// ---------------- fallback (R1-style, only if workspace too small) ----------

__global__ __launch_bounds__(256) void f_init_deg(unsigned* deg, int n) {
    int i = blockIdx.x * 256 + threadIdx.x;
    if (i < n) deg[i] = 1u;
}
__global__ __launch_bounds__(256) void f_count_deg(const int* dst, unsigned* deg, int E) {
    int e = blockIdx.x * 256 + threadIdx.x;
    if (e < E) atomicAdd(&deg[dst[e]], 1u);
}
__global__ __launch_bounds__(256) void f_node1(const float2* x, const float* W1,
                                               const unsigned* deg, float* dinv,
                                               float4* h1s, float4* agg1, int n) {
    int i = blockIdx.x * 256 + threadIdx.x;
    if (i >= n) return;
    float dv = 1.0f / sqrtf((float)deg[i]);
    dinv[i] = dv;
    float2 xv = x[i];
    float4 h;
    h.x = fmaf(xv.y, W1[4], xv.x * W1[0]) * dv;
    h.y = fmaf(xv.y, W1[5], xv.x * W1[1]) * dv;
    h.z = fmaf(xv.y, W1[6], xv.x * W1[2]) * dv;
    h.w = fmaf(xv.y, W1[7], xv.x * W1[3]) * dv;
    h1s[i] = h;
    agg1[i] = make_float4(h.x * dv, h.y * dv, h.z * dv, h.w * dv);
}
__global__ __launch_bounds__(256) void f_edge1(const int* src, const int* dst,
                                               const float* dinv, const float4* h1s,
                                               float* agg1, int E) {
    int e = blockIdx.x * 256 + threadIdx.x;
    if (e >= E) return;
    int s = src[e], d = dst[e];
    float w = dinv[d];
    float4 m = h1s[s];
    float* p = agg1 + 4ll * d;
    unsafeAtomicAdd(p + 0, m.x * w);
    unsafeAtomicAdd(p + 1, m.y * w);
    unsafeAtomicAdd(p + 2, m.z * w);
    unsafeAtomicAdd(p + 3, m.w * w);
}
__global__ __launch_bounds__(256) void f_node2(const float4* agg1, const float* b1,
                                               const float* W2, const float* b2,
                                               const float* dinv, float2* h2s,
                                               float2* out, int n) {
    int i = blockIdx.x * 256 + threadIdx.x;
    if (i >= n) return;
    float4 a = agg1[i];
    a.x = fmaxf(a.x + b1[0], 0.0f);
    a.y = fmaxf(a.y + b1[1], 0.0f);
    a.z = fmaxf(a.z + b1[2], 0.0f);
    a.w = fmaxf(a.w + b1[3], 0.0f);
    float dv = dinv[i];
    float2 h;
    h.x = (a.x * W2[0] + a.y * W2[2] + a.z * W2[4] + a.w * W2[6]) * dv;
    h.y = (a.x * W2[1] + a.y * W2[3] + a.z * W2[5] + a.w * W2[7]) * dv;
    h2s[i] = h;
    out[i] = make_float2(b2[0] + h.x * dv, b2[1] + h.y * dv);
}
__global__ __launch_bounds__(256) void f_edge2(const int* src, const int* dst,
                                               const float* dinv, const float2* h2s,
                                               float* out, int E) {
    int e = blockIdx.x * 256 + threadIdx.x;
    if (e >= E) return;
    int s = src[e], d = dst[e];
    float w = dinv[d];
    float2 m = h2s[s];
    float* p = out + 2ll * d;
    unsafeAtomicAdd(p + 0, m.x * w);
    unsafeAtomicAdd(p + 1, m.y * w);
}

extern "C" void kernel_launch(void* const* d_in, const int* in_sizes, int n_in,
                              void* d_out, int out_size, void* d_ws, size_t ws_size,
                              hipStream_t stream) {
    const float* x  = (const float*)d_in[0];
    const int* ei   = (const int*)d_in[1];
    const float* W1 = (const float*)d_in[2];
    const float* b1 = (const float*)d_in[3];
    const float* W2 = (const float*)d_in[4];
    const float* b2 = (const float*)d_in[5];
    float* out = (float*)d_out;

    const int N = in_sizes[0] / 2;
    const int E = in_sizes[1] / 2;
    const int* src = ei;
    const int* dst = ei + E;
    const int NB = (N + W - 1) >> W_SHIFT;

    char* ws = (char*)d_ws;
    const int gN = (N + 255) / 256;
    const int gE = (E + 255) / 256;

    // slab capacity: mean fill E/NB (~32.7K, sigma~181); margin 4096 (>20σ)
    size_t fixed = 32768 + (size_t)16 * N;   // fill | dinv | deg | xs | h2s
    long avail = (long)ws_size - (long)fixed;
    long Cmax = (avail > 0) ? avail / (4L * NB) : 0;
    long Cmin = (long)(E / (NB > 0 ? NB : 1)) + 4096;
    long Cw = (Cmax > Cmin + 8192) ? (Cmin + 8192) : Cmax;
    unsigned C = (unsigned)(Cw & ~3L);       // multiple of 4 for uint4 loads
    bool fast = ((long)C >= Cmin) && (NB <= MAXB) && (N <= (1 << 20));

    if (fast) {
        unsigned* fill = (unsigned*)(ws);                          // NB entries
        float*    dinv = (float*)(ws + 32768);
        unsigned* deg  = (unsigned*)(ws + 32768 + (size_t)4 * N);
        __half2*  xs   = (__half2*)(ws + 32768 + (size_t)8 * N);
        __half2*  h2s  = (__half2*)(ws + 32768 + (size_t)12 * N);
        unsigned* perm = (unsigned*)(ws + fixed);

        k_zero_fill<<<(NB + 255) / 256, 256, 0, stream>>>(fill, NB, C);
        k_reorder<<<(E + CHUNK - 1) / CHUNK, RB, 0, stream>>>(src, dst, fill, perm, E);
        k_dinv<<<NB, AB, 0, stream>>>(perm, fill, (const float2*)x, dinv, deg, xs, N, C);
        k_acc1<<<NB, AB, 0, stream>>>(perm, fill, xs, dinv, deg, W1, b1, W2, h2s, N, C);
        k_acc2<<<NB, AB, 0, stream>>>(perm, fill, h2s, dinv, deg, b2, (float2*)out, N, C);
    } else {
        unsigned* deg = (unsigned*)(ws);
        float* dinv   = (float*)(ws + (size_t)4 * N);
        float* h1s    = (float*)(ws + (size_t)8 * N);
        float* agg1   = (float*)(ws + (size_t)24 * N);
        float* h2s    = h1s;

        f_init_deg<<<gN, 256, 0, stream>>>(deg, N);
        f_count_deg<<<gE, 256, 0, stream>>>(dst, deg, E);
        f_node1<<<gN, 256, 0, stream>>>((const float2*)x, W1, deg, dinv,
                                        (float4*)h1s, (float4*)agg1, N);
        f_edge1<<<gE, 256, 0, stream>>>(src, dst, dinv, (const float4*)h1s, agg1, E);
        f_node2<<<gN, 256, 0, stream>>>((const float4*)agg1, b1, W2, b2, dinv,
                                        (float2*)h2s, (float2*)out, N);
        f_edge2<<<gE, 256, 0, stream>>>(src, dst, dinv, (const float2*)h2s, out, E);
    }
}

// Round 8
// 434.673 us; speedup vs baseline: 12.5480x; 1.0331x over previous
//
#include <hip/hip_runtime.h>
#include <hip/hip_fp16.h>

// GCN 2-layer forward, MI355X. R8: LDS-accumulator replication + 8-deep gather.
// vs R7 (449us; acc invariant across occupancy 33%<->95% => per-CU pipe bound
// at 3.95 cyc/edge = gather-L1-lookup + u64 LDS atomic; 2.08M bank conflicts):
//  - acc1/acc2 accumulate into 2 replicated LDS banks (u64 acc[2*W], lane
//    parity selects copy, summed at flush) -> same-bank collisions halved.
//  - dinv histogram replicated the same way (u32 c[2*W]).
//  - per-edge loops unrolled x8 (two uint4 perm loads in flight).
// Kept: W=2048 slab multisplit reorder, 1x u64 fixed-point LDS atomic/edge,
// fused MLP flush in acc1, half2 L2-resident gather tables.
// Pipeline: zero(fill=b*C), reorder, dinv(+deg+xs), acc1(+full MLP), acc2.

constexpr int W_SHIFT = 11;
constexpr int W = 2048;            // nodes per dst window
constexpr int MAXB = 512;          // max buckets
constexpr int RB = 1024;           // reorder block threads
constexpr int CHUNK = 8192;        // edges per reorder block
constexpr int AB = 512;            // accumulate block threads

constexpr float SCALE1 = 65536.0f;        // 2^16
constexpr float INV1   = 1.0f / 65536.0f;
constexpr unsigned BIAS1 = 1u << 20;
constexpr float SCALE2 = 4096.0f;         // 2^12
constexpr float INV2   = 1.0f / 4096.0f;
constexpr unsigned BIAS2 = 1u << 22;

typedef unsigned uv4 __attribute__((ext_vector_type(4)));
typedef int      iv4 __attribute__((ext_vector_type(4)));

__device__ __forceinline__ unsigned long long pack2(float a, float b,
                                                    float scale, unsigned bias) {
    unsigned lo = (unsigned)(__float2int_rn(a * scale) + (int)bias);
    unsigned hi = (unsigned)(__float2int_rn(b * scale) + (int)bias);
    return (unsigned long long)lo | ((unsigned long long)hi << 32);
}

__global__ __launch_bounds__(256) void k_zero_fill(unsigned* __restrict__ fill,
                                                   int nb, unsigned C) {
    int i = blockIdx.x * 256 + threadIdx.x;
    if (i < nb) fill[i] = (unsigned)i * C;
}

// LDS multisplit: bin CHUNK edges into dst windows with coalesced output.
__global__ __launch_bounds__(RB) void k_reorder(const int* __restrict__ src,
                                                const int* __restrict__ dst,
                                                unsigned* __restrict__ fill,
                                                unsigned* __restrict__ perm, int E) {
    __shared__ unsigned hist[MAXB];       // counts -> running local ptr
    __shared__ unsigned lbase[MAXB];      // scan scratch -> inclusive scan
    __shared__ unsigned gdelta[MAXB];     // globalBase - localBase
    __shared__ unsigned sorted[CHUNK];    // vals in locally-sorted order
    __shared__ unsigned short sbb[CHUNK]; // bucket of sorted[t]
    int tid = threadIdx.x;
    if (tid < MAXB) hist[tid] = 0u;
    __syncthreads();
    long base0 = (long)blockIdx.x * CHUNK;
    int total = (int)min((long)CHUNK, (long)E - base0);
    bool full = (total == CHUNK);

    if (full) {
        const iv4* dv4 = (const iv4*)(dst + base0);
        #pragma unroll
        for (int k = 0; k < 2; k++) {
            iv4 q = dv4[k * RB + tid];
            atomicAdd(&hist[((unsigned)q.x) >> W_SHIFT], 1u);
            atomicAdd(&hist[((unsigned)q.y) >> W_SHIFT], 1u);
            atomicAdd(&hist[((unsigned)q.z) >> W_SHIFT], 1u);
            atomicAdd(&hist[((unsigned)q.w) >> W_SHIFT], 1u);
        }
    } else {
        for (int li = tid; li < total; li += RB)
            atomicAdd(&hist[((unsigned)dst[base0 + li]) >> W_SHIFT], 1u);
    }
    __syncthreads();
    // inclusive Hillis-Steele scan over MAXB buckets
    unsigned v = (tid < MAXB) ? hist[tid] : 0u;
    if (tid < MAXB) lbase[tid] = v;
    __syncthreads();
    for (int off = 1; off < MAXB; off <<= 1) {
        unsigned u = (tid >= off && tid < MAXB) ? lbase[tid - off] : 0u;
        __syncthreads();
        if (tid < MAXB) lbase[tid] += u;
        __syncthreads();
    }
    if (tid < MAXB) {
        unsigned excl = lbase[tid] - v;
        unsigned gd = 0u;
        if (v) gd = atomicAdd(&fill[tid], v) - excl;  // reserve slab space
        gdelta[tid] = gd;
        hist[tid] = excl;   // running local write ptr
    }
    __syncthreads();
    if (full) {
        const iv4* dv4 = (const iv4*)(dst + base0);
        const iv4* sv4 = (const iv4*)(src + base0);
        #pragma unroll
        for (int k = 0; k < 2; k++) {
            iv4 dq = dv4[k * RB + tid];
            iv4 sq = sv4[k * RB + tid];
            unsigned d, b, lpos;
            d = (unsigned)dq.x; b = d >> W_SHIFT; lpos = atomicAdd(&hist[b], 1u);
            sorted[lpos] = (unsigned)sq.x | ((d & (W - 1)) << 20); sbb[lpos] = (unsigned short)b;
            d = (unsigned)dq.y; b = d >> W_SHIFT; lpos = atomicAdd(&hist[b], 1u);
            sorted[lpos] = (unsigned)sq.y | ((d & (W - 1)) << 20); sbb[lpos] = (unsigned short)b;
            d = (unsigned)dq.z; b = d >> W_SHIFT; lpos = atomicAdd(&hist[b], 1u);
            sorted[lpos] = (unsigned)sq.z | ((d & (W - 1)) << 20); sbb[lpos] = (unsigned short)b;
            d = (unsigned)dq.w; b = d >> W_SHIFT; lpos = atomicAdd(&hist[b], 1u);
            sorted[lpos] = (unsigned)sq.w | ((d & (W - 1)) << 20); sbb[lpos] = (unsigned short)b;
        }
    } else {
        for (int li = tid; li < total; li += RB) {
            unsigned d = (unsigned)dst[base0 + li];
            unsigned s = (unsigned)src[base0 + li];
            unsigned b = d >> W_SHIFT;
            unsigned lpos = atomicAdd(&hist[b], 1u);
            sorted[lpos] = s | ((d & (W - 1)) << 20);
            sbb[lpos] = (unsigned short)b;
        }
    }
    __syncthreads();
    if (full) {
        #pragma unroll
        for (int k = 0; k < CHUNK / RB; k++) {
            int t = k * RB + tid;
            unsigned b = sbb[t];
            perm[gdelta[b] + t] = sorted[t];   // piecewise-contiguous targets
        }
    } else {
        for (int t = tid; t < total; t += RB) {
            unsigned b = sbb[t];
            perm[gdelta[b] + t] = sorted[t];
        }
    }
}

// degree count (x2-replicated LDS histogram) + dinv + deg + xs, fused
__global__ __launch_bounds__(AB) void k_dinv(const unsigned* __restrict__ perm,
                                             const unsigned* __restrict__ fill,
                                             const float2* __restrict__ x,
                                             float* __restrict__ dinv,
                                             unsigned* __restrict__ deg,
                                             __half2* __restrict__ xs,
                                             int N, unsigned C) {
    __shared__ unsigned c[2 * W];
    for (int i = threadIdx.x; i < 2 * W; i += AB) c[i] = 0u;
    __syncthreads();
    int b = blockIdx.x;
    unsigned par = threadIdx.x & 1u;
    unsigned s = (unsigned)b * C, e = fill[b];
    unsigned m = e - s, nv8 = m >> 3;
    const uv4* p4 = (const uv4*)(perm + s);
    for (unsigned j = threadIdx.x; j < nv8; j += AB) {
        uv4 qa = __builtin_nontemporal_load(p4 + 2u * j);
        uv4 qb = __builtin_nontemporal_load(p4 + 2u * j + 1u);
        atomicAdd(&c[((qa.x >> 20) << 1) | par], 1u);
        atomicAdd(&c[((qa.y >> 20) << 1) | par], 1u);
        atomicAdd(&c[((qa.z >> 20) << 1) | par], 1u);
        atomicAdd(&c[((qa.w >> 20) << 1) | par], 1u);
        atomicAdd(&c[((qb.x >> 20) << 1) | par], 1u);
        atomicAdd(&c[((qb.y >> 20) << 1) | par], 1u);
        atomicAdd(&c[((qb.z >> 20) << 1) | par], 1u);
        atomicAdd(&c[((qb.w >> 20) << 1) | par], 1u);
    }
    unsigned t = s + (nv8 << 3) + threadIdx.x;
    if (t < e) atomicAdd(&c[((perm[t] >> 20) << 1) | par], 1u);
    __syncthreads();
    int d0 = b << W_SHIFT;
    for (int l = threadIdx.x; l < W; l += AB) {
        int d = d0 + l;
        if (d < N) {
            unsigned cn = c[2 * l] + c[2 * l + 1];
            float dv = 1.0f / sqrtf((float)(cn + 1u));  // +1 self-loop
            dinv[d] = dv;
            deg[d] = cn;
            float2 xv = x[d];
            xs[d] = __floats2half2_rn(xv.x * dv, xv.y * dv);
        }
    }
}

// layer1 aggregate (1 u64 fixed-point atomic/edge, x2-replicated acc) + MLP
__global__ __launch_bounds__(AB) void k_acc1(const unsigned* __restrict__ perm,
                                             const unsigned* __restrict__ fill,
                                             const __half2* __restrict__ xs,
                                             const float* __restrict__ dinv,
                                             const unsigned* __restrict__ deg,
                                             const float* __restrict__ W1,
                                             const float* __restrict__ b1,
                                             const float* __restrict__ W2,
                                             __half2* __restrict__ h2s,
                                             int N, unsigned C) {
    __shared__ unsigned long long acc[2 * W];
    for (int i = threadIdx.x; i < 2 * W; i += AB) acc[i] = 0ull;
    __syncthreads();
    int b = blockIdx.x;
    unsigned par = threadIdx.x & 1u;
    unsigned s = (unsigned)b * C, e = fill[b];
    unsigned m = e - s, nv8 = m >> 3;
    const uv4* p4 = (const uv4*)(perm + s);
    for (unsigned j = threadIdx.x; j < nv8; j += AB) {
        uv4 qa = __builtin_nontemporal_load(p4 + 2u * j);
        uv4 qb = __builtin_nontemporal_load(p4 + 2u * j + 1u);
        float2 v0 = __half22float2(xs[qa.x & 0xFFFFFu]);
        float2 v1 = __half22float2(xs[qa.y & 0xFFFFFu]);
        float2 v2 = __half22float2(xs[qa.z & 0xFFFFFu]);
        float2 v3 = __half22float2(xs[qa.w & 0xFFFFFu]);
        float2 v4 = __half22float2(xs[qb.x & 0xFFFFFu]);
        float2 v5 = __half22float2(xs[qb.y & 0xFFFFFu]);
        float2 v6 = __half22float2(xs[qb.z & 0xFFFFFu]);
        float2 v7 = __half22float2(xs[qb.w & 0xFFFFFu]);
        atomicAdd(&acc[((qa.x >> 20) << 1) | par], pack2(v0.x, v0.y, SCALE1, BIAS1));
        atomicAdd(&acc[((qa.y >> 20) << 1) | par], pack2(v1.x, v1.y, SCALE1, BIAS1));
        atomicAdd(&acc[((qa.z >> 20) << 1) | par], pack2(v2.x, v2.y, SCALE1, BIAS1));
        atomicAdd(&acc[((qa.w >> 20) << 1) | par], pack2(v3.x, v3.y, SCALE1, BIAS1));
        atomicAdd(&acc[((qb.x >> 20) << 1) | par], pack2(v4.x, v4.y, SCALE1, BIAS1));
        atomicAdd(&acc[((qb.y >> 20) << 1) | par], pack2(v5.x, v5.y, SCALE1, BIAS1));
        atomicAdd(&acc[((qb.z >> 20) << 1) | par], pack2(v6.x, v6.y, SCALE1, BIAS1));
        atomicAdd(&acc[((qb.w >> 20) << 1) | par], pack2(v7.x, v7.y, SCALE1, BIAS1));
    }
    unsigned t = s + (nv8 << 3) + threadIdx.x;
    if (t < e) {
        unsigned p = perm[t];
        float2 v = __half22float2(xs[p & 0xFFFFFu]);
        atomicAdd(&acc[((p >> 20) << 1) | par], pack2(v.x, v.y, SCALE1, BIAS1));
    }
    __syncthreads();
    int d0 = b << W_SHIFT;
    float w10 = W1[0], w11 = W1[1], w12 = W1[2], w13 = W1[3];
    float w14 = W1[4], w15 = W1[5], w16 = W1[6], w17 = W1[7];
    float bb0 = b1[0], bb1 = b1[1], bb2 = b1[2], bb3 = b1[3];
    float u0 = W2[0], u1 = W2[1], u2 = W2[2], u3 = W2[3];
    float u4 = W2[4], u5 = W2[5], u6 = W2[6], u7 = W2[7];
    for (int l = threadIdx.x; l < W; l += AB) {
        int d = d0 + l;
        if (d < N) {
            float dv = dinv[d];
            unsigned cn = deg[d];
            unsigned long long a64 = acc[2 * l] + acc[2 * l + 1];
            unsigned lo = (unsigned)a64, hi = (unsigned)(a64 >> 32);
            float2 self = __half22float2(xs[d]);
            float Sx = (float)(int)(lo - cn * BIAS1) * INV1 + self.x;
            float Sy = (float)(int)(hi - cn * BIAS1) * INV1 + self.y;
            float a0 = fmaxf(fmaf(Sy, w14, Sx * w10) * dv + bb0, 0.0f);
            float a1 = fmaxf(fmaf(Sy, w15, Sx * w11) * dv + bb1, 0.0f);
            float a2 = fmaxf(fmaf(Sy, w16, Sx * w12) * dv + bb2, 0.0f);
            float a3 = fmaxf(fmaf(Sy, w17, Sx * w13) * dv + bb3, 0.0f);
            float hx = (a0 * u0 + a1 * u2 + a2 * u4 + a3 * u6) * dv;
            float hy = (a0 * u1 + a1 * u3 + a2 * u5 + a3 * u7) * dv;
            h2s[d] = __floats2half2_rn(hx, hy);
        }
    }
}

__global__ __launch_bounds__(AB) void k_acc2(const unsigned* __restrict__ perm,
                                             const unsigned* __restrict__ fill,
                                             const __half2* __restrict__ h2s,
                                             const float* __restrict__ dinv,
                                             const unsigned* __restrict__ deg,
                                             const float* __restrict__ b2,
                                             float2* __restrict__ out,
                                             int N, unsigned C) {
    __shared__ unsigned long long acc[2 * W];
    for (int i = threadIdx.x; i < 2 * W; i += AB) acc[i] = 0ull;
    __syncthreads();
    int b = blockIdx.x;
    unsigned par = threadIdx.x & 1u;
    unsigned s = (unsigned)b * C, e = fill[b];
    unsigned m = e - s, nv8 = m >> 3;
    const uv4* p4 = (const uv4*)(perm + s);
    for (unsigned j = threadIdx.x; j < nv8; j += AB) {
        uv4 qa = __builtin_nontemporal_load(p4 + 2u * j);
        uv4 qb = __builtin_nontemporal_load(p4 + 2u * j + 1u);
        float2 v0 = __half22float2(h2s[qa.x & 0xFFFFFu]);
        float2 v1 = __half22float2(h2s[qa.y & 0xFFFFFu]);
        float2 v2 = __half22float2(h2s[qa.z & 0xFFFFFu]);
        float2 v3 = __half22float2(h2s[qa.w & 0xFFFFFu]);
        float2 v4 = __half22float2(h2s[qb.x & 0xFFFFFu]);
        float2 v5 = __half22float2(h2s[qb.y & 0xFFFFFu]);
        float2 v6 = __half22float2(h2s[qb.z & 0xFFFFFu]);
        float2 v7 = __half22float2(h2s[qb.w & 0xFFFFFu]);
        atomicAdd(&acc[((qa.x >> 20) << 1) | par], pack2(v0.x, v0.y, SCALE2, BIAS2));
        atomicAdd(&acc[((qa.y >> 20) << 1) | par], pack2(v1.x, v1.y, SCALE2, BIAS2));
        atomicAdd(&acc[((qa.z >> 20) << 1) | par], pack2(v2.x, v2.y, SCALE2, BIAS2));
        atomicAdd(&acc[((qa.w >> 20) << 1) | par], pack2(v3.x, v3.y, SCALE2, BIAS2));
        atomicAdd(&acc[((qb.x >> 20) << 1) | par], pack2(v4.x, v4.y, SCALE2, BIAS2));
        atomicAdd(&acc[((qb.y >> 20) << 1) | par], pack2(v5.x, v5.y, SCALE2, BIAS2));
        atomicAdd(&acc[((qb.z >> 20) << 1) | par], pack2(v6.x, v6.y, SCALE2, BIAS2));
        atomicAdd(&acc[((qb.w >> 20) << 1) | par], pack2(v7.x, v7.y, SCALE2, BIAS2));
    }
    unsigned t = s + (nv8 << 3) + threadIdx.x;
    if (t < e) {
        unsigned p = perm[t];
        float2 v = __half22float2(h2s[p & 0xFFFFFu]);
        atomicAdd(&acc[((p >> 20) << 1) | par], pack2(v.x, v.y, SCALE2, BIAS2));
    }
    __syncthreads();
    int d0 = b << W_SHIFT;
    float bb0 = b2[0], bb1 = b2[1];
    for (int l = threadIdx.x; l < W; l += AB) {
        int d = d0 + l;
        if (d < N) {
            float dv = dinv[d];
            unsigned cn = deg[d];
            unsigned long long a64 = acc[2 * l] + acc[2 * l + 1];
            unsigned lo = (unsigned)a64, hi = (unsigned)(a64 >> 32);
            float2 v = __half22float2(h2s[d]);
            float Sx = (float)(int)(lo - cn * BIAS2) * INV2 + v.x;
            float Sy = (float)(int)(hi - cn * BIAS2) * INV2 + v.y;
            out[d] = make_float2(Sx * dv + bb0, Sy * dv + bb1);
        }
    }
}

// ---------------- fallback (R1-style, only if workspace too small) ----------

__global__ __launch_bounds__(256) void f_init_deg(unsigned* deg, int n) {
    int i = blockIdx.x * 256 + threadIdx.x;
    if (i < n) deg[i] = 1u;
}
__global__ __launch_bounds__(256) void f_count_deg(const int* dst, unsigned* deg, int E) {
    int e = blockIdx.x * 256 + threadIdx.x;
    if (e < E) atomicAdd(&deg[dst[e]], 1u);
}
__global__ __launch_bounds__(256) void f_node1(const float2* x, const float* W1,
                                               const unsigned* deg, float* dinv,
                                               float4* h1s, float4* agg1, int n) {
    int i = blockIdx.x * 256 + threadIdx.x;
    if (i >= n) return;
    float dv = 1.0f / sqrtf((float)deg[i]);
    dinv[i] = dv;
    float2 xv = x[i];
    float4 h;
    h.x = fmaf(xv.y, W1[4], xv.x * W1[0]) * dv;
    h.y = fmaf(xv.y, W1[5], xv.x * W1[1]) * dv;
    h.z = fmaf(xv.y, W1[6], xv.x * W1[2]) * dv;
    h.w = fmaf(xv.y, W1[7], xv.x * W1[3]) * dv;
    h1s[i] = h;
    agg1[i] = make_float4(h.x * dv, h.y * dv, h.z * dv, h.w * dv);
}
__global__ __launch_bounds__(256) void f_edge1(const int* src, const int* dst,
                                               const float* dinv, const float4* h1s,
                                               float* agg1, int E) {
    int e = blockIdx.x * 256 + threadIdx.x;
    if (e >= E) return;
    int s = src[e], d = dst[e];
    float w = dinv[d];
    float4 m = h1s[s];
    float* p = agg1 + 4ll * d;
    unsafeAtomicAdd(p + 0, m.x * w);
    unsafeAtomicAdd(p + 1, m.y * w);
    unsafeAtomicAdd(p + 2, m.z * w);
    unsafeAtomicAdd(p + 3, m.w * w);
}
__global__ __launch_bounds__(256) void f_node2(const float4* agg1, const float* b1,
                                               const float* W2, const float* b2,
                                               const float* dinv, float2* h2s,
                                               float2* out, int n) {
    int i = blockIdx.x * 256 + threadIdx.x;
    if (i >= n) return;
    float4 a = agg1[i];
    a.x = fmaxf(a.x + b1[0], 0.0f);
    a.y = fmaxf(a.y + b1[1], 0.0f);
    a.z = fmaxf(a.z + b1[2], 0.0f);
    a.w = fmaxf(a.w + b1[3], 0.0f);
    float dv = dinv[i];
    float2 h;
    h.x = (a.x * W2[0] + a.y * W2[2] + a.z * W2[4] + a.w * W2[6]) * dv;
    h.y = (a.x * W2[1] + a.y * W2[3] + a.z * W2[5] + a.w * W2[7]) * dv;
    h2s[i] = h;
    out[i] = make_float2(b2[0] + h.x * dv, b2[1] + h.y * dv);
}
__global__ __launch_bounds__(256) void f_edge2(const int* src, const int* dst,
                                               const float* dinv, const float2* h2s,
                                               float* out, int E) {
    int e = blockIdx.x * 256 + threadIdx.x;
    if (e >= E) return;
    int s = src[e], d = dst[e];
    float w = dinv[d];
    float2 m = h2s[s];
    float* p = out + 2ll * d;
    unsafeAtomicAdd(p + 0, m.x * w);
    unsafeAtomicAdd(p + 1, m.y * w);
}

extern "C" void kernel_launch(void* const* d_in, const int* in_sizes, int n_in,
                              void* d_out, int out_size, void* d_ws, size_t ws_size,
                              hipStream_t stream) {
    const float* x  = (const float*)d_in[0];
    const int* ei   = (const int*)d_in[1];
    const float* W1 = (const float*)d_in[2];
    const float* b1 = (const float*)d_in[3];
    const float* W2 = (const float*)d_in[4];
    const float* b2 = (const float*)d_in[5];
    float* out = (float*)d_out;

    const int N = in_sizes[0] / 2;
    const int E = in_sizes[1] / 2;
    const int* src = ei;
    const int* dst = ei + E;
    const int NB = (N + W - 1) >> W_SHIFT;

    char* ws = (char*)d_ws;
    const int gN = (N + 255) / 256;
    const int gE = (E + 255) / 256;

    // slab capacity: mean fill E/NB (~32.7K, sigma~181); margin 4096 (>20σ)
    size_t fixed = 32768 + (size_t)16 * N;   // fill | dinv | deg | xs | h2s
    long avail = (long)ws_size - (long)fixed;
    long Cmax = (avail > 0) ? avail / (4L * NB) : 0;
    long Cmin = (long)(E / (NB > 0 ? NB : 1)) + 4096;
    long Cw = (Cmax > Cmin + 8192) ? (Cmin + 8192) : Cmax;
    unsigned C = (unsigned)(Cw & ~7L);       // multiple of 8 for uint4x2 loads
    bool fast = ((long)C >= Cmin) && (NB <= MAXB) && (N <= (1 << 20));

    if (fast) {
        unsigned* fill = (unsigned*)(ws);                          // NB entries
        float*    dinv = (float*)(ws + 32768);
        unsigned* deg  = (unsigned*)(ws + 32768 + (size_t)4 * N);
        __half2*  xs   = (__half2*)(ws + 32768 + (size_t)8 * N);
        __half2*  h2s  = (__half2*)(ws + 32768 + (size_t)12 * N);
        unsigned* perm = (unsigned*)(ws + fixed);

        k_zero_fill<<<(NB + 255) / 256, 256, 0, stream>>>(fill, NB, C);
        k_reorder<<<(E + CHUNK - 1) / CHUNK, RB, 0, stream>>>(src, dst, fill, perm, E);
        k_dinv<<<NB, AB, 0, stream>>>(perm, fill, (const float2*)x, dinv, deg, xs, N, C);
        k_acc1<<<NB, AB, 0, stream>>>(perm, fill, xs, dinv, deg, W1, b1, W2, h2s, N, C);
        k_acc2<<<NB, AB, 0, stream>>>(perm, fill, h2s, dinv, deg, b2, (float2*)out, N, C);
    } else {
        unsigned* deg = (unsigned*)(ws);
        float* dinv   = (float*)(ws + (size_t)4 * N);
        float* h1s    = (float*)(ws + (size_t)8 * N);
        float* agg1   = (float*)(ws + (size_t)24 * N);
        float* h2s    = h1s;

        f_init_deg<<<gN, 256, 0, stream>>>(deg, N);
        f_count_deg<<<gE, 256, 0, stream>>>(dst, deg, E);
        f_node1<<<gN, 256, 0, stream>>>((const float2*)x, W1, deg, dinv,
                                        (float4*)h1s, (float4*)agg1, N);
        f_edge1<<<gE, 256, 0, stream>>>(src, dst, dinv, (const float4*)h1s, agg1, E);
        f_node2<<<gN, 256, 0, stream>>>((const float4*)agg1, b1, W2, b2, dinv,
                                        (float2*)h2s, (float2*)out, N);
        f_edge2<<<gE, 256, 0, stream>>>(src, dst, dinv, (const float2*)h2s, out, E);
    }
}